// Round 1
// baseline (601.385 us; speedup 1.0000x reference)
//
#include <hip/hip_runtime.h>

#define D 128

// ---------------- CSR build ----------------

__global__ void init_kernel(int* dout, int* din, int* cur, int N) {
  int i = blockIdx.x * blockDim.x + threadIdx.x;
  if (i < N) { dout[i] = 0; din[i] = 0; cur[i] = 0; }
}

__global__ void count_kernel(const int* __restrict__ src, const int* __restrict__ dst,
                             int* dout, int* din, int E) {
  int e = blockIdx.x * blockDim.x + threadIdx.x;
  if (e < E) {
    atomicAdd(&dout[src[e]], 1);
    atomicAdd(&din[dst[e]], 1);
  }
}

// exclusive prefix sum of din -> roff[0..N], single block of 1024 threads,
// wave-level shfl scan (2 barriers per 1024-chunk)
__global__ void scan_kernel(const int* __restrict__ din, int* __restrict__ roff, int N) {
  __shared__ int wsum[16];
  __shared__ int carry_s;
  const int t = threadIdx.x, lane = t & 63, wid = t >> 6;
  if (t == 0) carry_s = 0;
  __syncthreads();
  for (int base = 0; base < N; base += 1024) {
    int i = base + t;
    int v = (i < N) ? din[i] : 0;
    int x = v;
    #pragma unroll
    for (int off = 1; off < 64; off <<= 1) {
      int u = __shfl_up(x, off);
      if (lane >= off) x += u;
    }
    if (lane == 63) wsum[wid] = x;           // inclusive wave total
    __syncthreads();
    if (t == 0) {
      int run = carry_s;
      #pragma unroll
      for (int w = 0; w < 16; ++w) { int s = wsum[w]; wsum[w] = run; run += s; }
      carry_s = run;
    }
    __syncthreads();
    if (i < N) roff[i] = wsum[wid] + (x - v); // wave base + exclusive-within-wave
    __syncthreads();                          // protect wsum before next chunk
  }
  if (t == 0) roff[N] = carry_s;
}

__global__ void norm_kernel(const int* __restrict__ dout, const int* __restrict__ din,
                            float* ns, float* nd, int N) {
  int i = blockIdx.x * blockDim.x + threadIdx.x;
  if (i < N) {
    ns[i] = rsqrtf((float)dout[i] + 1.0f);   // +1 self-loop
    nd[i] = rsqrtf((float)din[i] + 1.0f);
  }
}

__global__ void scatter_kernel(const int* __restrict__ src, const int* __restrict__ dst,
                               const int* __restrict__ roff, int* cursor, int* eout, int E) {
  int e = blockIdx.x * blockDim.x + threadIdx.x;
  if (e < E) {
    int d = dst[e];
    int pos = atomicAdd(&cursor[d], 1);
    eout[roff[d] + pos] = src[e];
  }
}

// ---------------- aggregation: 1 wave per node, float2 per lane ----------------
// out[node] = ( selfterm + sum_{e in CSR[node]} feat[src_e] * (SCALE ? nsrc[src_e] : 1) ) * ndst[node]
// selfterm = feat[node] * (SCALE ? nsrc[node] : 1)

template<bool SCALE>
__global__ __launch_bounds__(256)
void gather_kernel(const float* __restrict__ feat, const int* __restrict__ eidx,
                   const int* __restrict__ roff, const float* __restrict__ nsrc,
                   const float* __restrict__ ndst, float* __restrict__ out, int N)
{
  const int wid = threadIdx.x >> 6;
  const int lane = threadIdx.x & 63;
  const int node = blockIdx.x * 4 + wid;
  if (node >= N) return;
  const int c = lane * 2;
  float2 acc = *(const float2*)(feat + (size_t)node * D + c);
  if (SCALE) { float s = nsrc[node]; acc.x *= s; acc.y *= s; }
  const int beg = roff[node], end = roff[node + 1];
  for (int e0 = beg; e0 < end; e0 += 64) {
    const int cnt = min(64, end - e0);
    int id = (lane < cnt) ? eidx[e0 + lane] : 0;
    int j = 0;
    for (; j + 4 <= cnt; j += 4) {           // 4 independent gathers in flight
      int s0 = __shfl(id, j);
      int s1 = __shfl(id, j + 1);
      int s2 = __shfl(id, j + 2);
      int s3 = __shfl(id, j + 3);
      float2 v0 = *(const float2*)(feat + (size_t)s0 * D + c);
      float2 v1 = *(const float2*)(feat + (size_t)s1 * D + c);
      float2 v2 = *(const float2*)(feat + (size_t)s2 * D + c);
      float2 v3 = *(const float2*)(feat + (size_t)s3 * D + c);
      if (SCALE) {
        float n0 = nsrc[s0], n1 = nsrc[s1], n2 = nsrc[s2], n3 = nsrc[s3];
        acc.x += v0.x * n0; acc.y += v0.y * n0;
        acc.x += v1.x * n1; acc.y += v1.y * n1;
        acc.x += v2.x * n2; acc.y += v2.y * n2;
        acc.x += v3.x * n3; acc.y += v3.y * n3;
      } else {
        acc.x += v0.x + v1.x + v2.x + v3.x;
        acc.y += v0.y + v1.y + v2.y + v3.y;
      }
    }
    for (; j < cnt; ++j) {
      int s = __shfl(id, j);
      float2 v = *(const float2*)(feat + (size_t)s * D + c);
      if (SCALE) { float n = nsrc[s]; acc.x += v.x * n; acc.y += v.y * n; }
      else       { acc.x += v.x; acc.y += v.y; }
    }
  }
  float nd = ndst[node];
  acc.x *= nd; acc.y *= nd;
  *(float2*)(out + (size_t)node * D + c) = acc;
}

// ---------------- fp32 GEMM: C[N,128] = A[N,128] @ W[128,128] + b (+ relu*nsrc) ----------------
// block: 64 rows x 128 cols, 256 threads, per-thread 4 rows x 8 cols.
// In-place safe (A==C): block reads its full A row-tile before writing the same rows.

template<bool RELU_SCALE>
__global__ __launch_bounds__(256)
void gemm128(const float* __restrict__ A, const float* __restrict__ W,
             const float* __restrict__ bias, const float* __restrict__ nsrc,
             float* __restrict__ C, int N)
{
  __shared__ float As[64][36];   // pad 36: 16B-aligned float4 writes, broadcast reads
  __shared__ float Bs[32][128];
  const int t = threadIdx.x;
  const int tx = t & 15;         // col group: cols 4*tx and 64+4*tx
  const int ty = t >> 4;         // row group: rows 4*ty..4*ty+3
  const int r0 = blockIdx.x * 64;
  float acc[4][8];
  #pragma unroll
  for (int j = 0; j < 4; ++j)
    #pragma unroll
    for (int cc = 0; cc < 8; ++cc) acc[j][cc] = 0.f;

  for (int kc = 0; kc < D; kc += 32) {
    __syncthreads();
    #pragma unroll
    for (int m = 0; m < 2; ++m) {            // stage A: 64x32
      int q = t * 2 + m;                      // 0..511 float4s
      int row = q >> 3;
      int fc = q & 7;
      int gr = r0 + row; if (gr > N - 1) gr = N - 1;
      float4 v = *(const float4*)(A + (size_t)gr * D + kc + fc * 4);
      *(float4*)(&As[row][fc * 4]) = v;
    }
    #pragma unroll
    for (int m = 0; m < 4; ++m) {            // stage B: 32x128
      int q = t + 256 * m;                    // 0..1023 float4s
      int kk = q >> 5;
      int fc = q & 31;
      float4 v = *(const float4*)(W + (size_t)(kc + kk) * D + fc * 4);
      *(float4*)(&Bs[kk][fc * 4]) = v;
    }
    __syncthreads();
    #pragma unroll
    for (int k = 0; k < 32; ++k) {
      float a0 = As[ty * 4 + 0][k];
      float a1 = As[ty * 4 + 1][k];
      float a2 = As[ty * 4 + 2][k];
      float a3 = As[ty * 4 + 3][k];
      float4 bv0 = *(const float4*)(&Bs[k][tx * 4]);
      float4 bv1 = *(const float4*)(&Bs[k][64 + tx * 4]);
      float b[8] = {bv0.x, bv0.y, bv0.z, bv0.w, bv1.x, bv1.y, bv1.z, bv1.w};
      #pragma unroll
      for (int cc = 0; cc < 8; ++cc) {
        acc[0][cc] += a0 * b[cc];
        acc[1][cc] += a1 * b[cc];
        acc[2][cc] += a2 * b[cc];
        acc[3][cc] += a3 * b[cc];
      }
    }
  }

  float4 bb0 = *(const float4*)(bias + tx * 4);
  float4 bb1 = *(const float4*)(bias + 64 + tx * 4);
  float bb[8] = {bb0.x, bb0.y, bb0.z, bb0.w, bb1.x, bb1.y, bb1.z, bb1.w};
  #pragma unroll
  for (int j = 0; j < 4; ++j) {
    int gr = r0 + ty * 4 + j;
    if (gr < N) {
      float s = RELU_SCALE ? nsrc[gr] : 1.0f;
      float o[8];
      #pragma unroll
      for (int cc = 0; cc < 8; ++cc) {
        float v = acc[j][cc] + bb[cc];
        if (RELU_SCALE) v = fmaxf(v, 0.f) * s;
        o[cc] = v;
      }
      *(float4*)(C + (size_t)gr * D + tx * 4) = make_float4(o[0], o[1], o[2], o[3]);
      *(float4*)(C + (size_t)gr * D + 64 + tx * 4) = make_float4(o[4], o[5], o[6], o[7]);
    }
  }
}

// ---------------- launch ----------------

extern "C" void kernel_launch(void* const* d_in, const int* in_sizes, int n_in,
                              void* d_out, int out_size, void* d_ws, size_t ws_size,
                              hipStream_t stream) {
  const float* feat = (const float*)d_in[0];
  const float* W1   = (const float*)d_in[1];
  const float* b1   = (const float*)d_in[2];
  const float* W2   = (const float*)d_in[3];
  const float* b2   = (const float*)d_in[4];
  const int*   src  = (const int*)d_in[5];
  const int*   dst  = (const int*)d_in[6];
  const int N = in_sizes[0] / D;
  const int E = in_sizes[5];
  float* out = (float*)d_out;

  auto align256 = [](size_t x) { return (x + 255) & ~(size_t)255; };
  char* p = (char*)d_ws;
  int*   deg_out = (int*)p;   p += align256((size_t)N * 4);
  int*   deg_in  = (int*)p;   p += align256((size_t)N * 4);
  int*   cursor  = (int*)p;   p += align256((size_t)N * 4);
  int*   row_off = (int*)p;   p += align256((size_t)(N + 1) * 4);
  float* nsrc    = (float*)p; p += align256((size_t)N * 4);
  float* ndst    = (float*)p; p += align256((size_t)N * 4);
  int*   esrc    = (int*)p;   p += align256((size_t)E * 4);
  float* h1s     = (float*)p; p += align256((size_t)N * D * 4);

  init_kernel<<<(N + 255) / 256, 256, 0, stream>>>(deg_out, deg_in, cursor, N);
  count_kernel<<<(E + 255) / 256, 256, 0, stream>>>(src, dst, deg_out, deg_in, E);
  scan_kernel<<<1, 1024, 0, stream>>>(deg_in, row_off, N);
  norm_kernel<<<(N + 255) / 256, 256, 0, stream>>>(deg_out, deg_in, nsrc, ndst, N);
  scatter_kernel<<<(E + 255) / 256, 256, 0, stream>>>(src, dst, row_off, cursor, esrc, E);

  // layer 1: agg -> d_out, gemm -> h1s (pre-scaled by nsrc, post-relu)
  gather_kernel<true><<<(N + 3) / 4, 256, 0, stream>>>(feat, esrc, row_off, nsrc, ndst, out, N);
  gemm128<true><<<(N + 63) / 64, 256, 0, stream>>>(out, W1, b1, nsrc, h1s, N);
  // layer 2: agg -> d_out, gemm in-place on d_out
  gather_kernel<false><<<(N + 3) / 4, 256, 0, stream>>>(h1s, esrc, row_off, nsrc, ndst, out, N);
  gemm128<false><<<(N + 63) / 64, 256, 0, stream>>>(out, W2, b2, nsrc, out, N);
}

// Round 4
// 470.716 us; speedup vs baseline: 1.2776x; 1.2776x over previous
//
#include <hip/hip_runtime.h>

#define D 128
#define RANGES 4
#define CHUNKS 32
#define BINS_MAX 12512   // >= ceil(50000/4)

// ---------------- CSR build, stage 1: per-chunk LDS histograms ----------------
// block b: r = b&3 (node range), k = b>>2 (edge chunk). Scalar loads.

__global__ __launch_bounds__(1024)
void hist_kernel(const int* __restrict__ keys, int* __restrict__ part,
                 int E, int N, int binsR, int chunkE)
{
  __shared__ int hist[BINS_MAX];
  const int b = blockIdx.x;
  const int r = b & (RANGES - 1);
  const int k = b >> 2;
  const int lo = r * binsR;
  const int hi = min(N, lo + binsR);
  const int nb = hi - lo;
  for (int i = threadIdx.x; i < nb; i += 1024) hist[i] = 0;
  __syncthreads();
  const int e0 = k * chunkE;
  const int e1 = min(E, e0 + chunkE);
  for (int e = e0 + threadIdx.x; e < e1; e += 1024) {
    int v = keys[e];
    if (v >= lo && v < hi) atomicAdd(&hist[v - lo], 1);
  }
  __syncthreads();
  for (int i = threadIdx.x; i < nb; i += 1024) part[(size_t)k * N + lo + i] = hist[i];
}

// per bin: out-deg -> nsrc; in-deg -> ndst, deg_in; pdst -> exclusive prefix over chunks
__global__ void reduce_kernel(const int* __restrict__ psrc, int* __restrict__ pdst,
                              int* __restrict__ deg_in, float* __restrict__ nsrc,
                              float* __restrict__ ndst, int N)
{
  int bin = blockIdx.x * blockDim.x + threadIdx.x;
  if (bin >= N) return;
  int runs = 0, rund = 0;
  for (int k = 0; k < CHUNKS; ++k) {
    runs += psrc[(size_t)k * N + bin];
    int vd = pdst[(size_t)k * N + bin];
    pdst[(size_t)k * N + bin] = rund;
    rund += vd;
  }
  deg_in[bin] = rund;
  nsrc[bin] = rsqrtf((float)runs + 1.0f);   // +1 self-loop
  ndst[bin] = rsqrtf((float)rund + 1.0f);
}

// exclusive prefix sum of din -> roff[0..N]  (ROUND-1 VERBATIM, proven)
__global__ void scan_kernel(const int* __restrict__ din, int* __restrict__ roff, int N) {
  __shared__ int wsum[16];
  __shared__ int carry_s;
  const int t = threadIdx.x, lane = t & 63, wid = t >> 6;
  if (t == 0) carry_s = 0;
  __syncthreads();
  for (int base = 0; base < N; base += 1024) {
    int i = base + t;
    int v = (i < N) ? din[i] : 0;
    int x = v;
    #pragma unroll
    for (int off = 1; off < 64; off <<= 1) {
      int u = __shfl_up(x, off);
      if (lane >= off) x += u;
    }
    if (lane == 63) wsum[wid] = x;           // inclusive wave total
    __syncthreads();
    if (t == 0) {
      int run = carry_s;
      #pragma unroll
      for (int w = 0; w < 16; ++w) { int s = wsum[w]; wsum[w] = run; run += s; }
      carry_s = run;
    }
    __syncthreads();
    if (i < N) roff[i] = wsum[wid] + (x - v); // wave base + exclusive-within-wave
    __syncthreads();                          // protect wsum before next chunk
  }
  if (t == 0) roff[N] = carry_s;
}

// scatter, deterministic: block (r,k); LDS cursor = roff[bin] + pdst[k][bin]; LDS atomics.
__global__ __launch_bounds__(1024)
void scatter_kernel(const int* __restrict__ src, const int* __restrict__ dst,
                    const int* __restrict__ pdst, const int* __restrict__ roff,
                    int* __restrict__ eout, int E, int N, int binsR, int chunkE)
{
  __shared__ int cur[BINS_MAX];
  const int b = blockIdx.x;
  const int r = b & (RANGES - 1);
  const int k = b >> 2;
  const int lo = r * binsR;
  const int hi = min(N, lo + binsR);
  const int nb = hi - lo;
  for (int i = threadIdx.x; i < nb; i += 1024)
    cur[i] = roff[lo + i] + pdst[(size_t)k * N + lo + i];
  __syncthreads();
  const int e0 = k * chunkE;
  const int e1 = min(E, e0 + chunkE);
  for (int e = e0 + threadIdx.x; e < e1; e += 1024) {
    int d = dst[e];
    if (d >= lo && d < hi) eout[atomicAdd(&cur[d - lo], 1)] = src[e];
  }
}

// ---------------- aggregation (ROUND-1 VERBATIM, proven): 1 wave/node, float2/lane --

template<bool SCALE>
__global__ __launch_bounds__(256)
void gather_kernel(const float* __restrict__ feat, const int* __restrict__ eidx,
                   const int* __restrict__ roff, const float* __restrict__ nsrc,
                   const float* __restrict__ ndst, float* __restrict__ out, int N)
{
  const int wid = threadIdx.x >> 6;
  const int lane = threadIdx.x & 63;
  const int node = blockIdx.x * 4 + wid;
  if (node >= N) return;
  const int c = lane * 2;
  float2 acc = *(const float2*)(feat + (size_t)node * D + c);
  if (SCALE) { float s = nsrc[node]; acc.x *= s; acc.y *= s; }
  const int beg = roff[node], end = roff[node + 1];
  for (int e0 = beg; e0 < end; e0 += 64) {
    const int cnt = min(64, end - e0);
    int id = (lane < cnt) ? eidx[e0 + lane] : 0;
    int j = 0;
    for (; j + 4 <= cnt; j += 4) {           // 4 independent gathers in flight
      int s0 = __shfl(id, j);
      int s1 = __shfl(id, j + 1);
      int s2 = __shfl(id, j + 2);
      int s3 = __shfl(id, j + 3);
      float2 v0 = *(const float2*)(feat + (size_t)s0 * D + c);
      float2 v1 = *(const float2*)(feat + (size_t)s1 * D + c);
      float2 v2 = *(const float2*)(feat + (size_t)s2 * D + c);
      float2 v3 = *(const float2*)(feat + (size_t)s3 * D + c);
      if (SCALE) {
        float n0 = nsrc[s0], n1 = nsrc[s1], n2 = nsrc[s2], n3 = nsrc[s3];
        acc.x += v0.x * n0; acc.y += v0.y * n0;
        acc.x += v1.x * n1; acc.y += v1.y * n1;
        acc.x += v2.x * n2; acc.y += v2.y * n2;
        acc.x += v3.x * n3; acc.y += v3.y * n3;
      } else {
        acc.x += v0.x + v1.x + v2.x + v3.x;
        acc.y += v0.y + v1.y + v2.y + v3.y;
      }
    }
    for (; j < cnt; ++j) {
      int s = __shfl(id, j);
      float2 v = *(const float2*)(feat + (size_t)s * D + c);
      if (SCALE) { float n = nsrc[s]; acc.x += v.x * n; acc.y += v.y * n; }
      else       { acc.x += v.x; acc.y += v.y; }
    }
  }
  float nd = ndst[node];
  acc.x *= nd; acc.y *= nd;
  *(float2*)(out + (size_t)node * D + c) = acc;
}

// ---------------- fp32 GEMM (ROUND-1 VERBATIM, proven) ----------------

template<bool RELU_SCALE>
__global__ __launch_bounds__(256)
void gemm128(const float* __restrict__ A, const float* __restrict__ W,
             const float* __restrict__ bias, const float* __restrict__ nsrc,
             float* __restrict__ C, int N)
{
  __shared__ float As[64][36];
  __shared__ float Bs[32][128];
  const int t = threadIdx.x;
  const int tx = t & 15;
  const int ty = t >> 4;
  const int r0 = blockIdx.x * 64;
  float acc[4][8];
  #pragma unroll
  for (int j = 0; j < 4; ++j)
    #pragma unroll
    for (int cc = 0; cc < 8; ++cc) acc[j][cc] = 0.f;

  for (int kc = 0; kc < D; kc += 32) {
    __syncthreads();
    #pragma unroll
    for (int m = 0; m < 2; ++m) {
      int q = t * 2 + m;
      int row = q >> 3;
      int fc = q & 7;
      int gr = r0 + row; if (gr > N - 1) gr = N - 1;
      float4 v = *(const float4*)(A + (size_t)gr * D + kc + fc * 4);
      *(float4*)(&As[row][fc * 4]) = v;
    }
    #pragma unroll
    for (int m = 0; m < 4; ++m) {
      int q = t + 256 * m;
      int kk = q >> 5;
      int fc = q & 31;
      float4 v = *(const float4*)(W + (size_t)(kc + kk) * D + fc * 4);
      *(float4*)(&Bs[kk][fc * 4]) = v;
    }
    __syncthreads();
    #pragma unroll
    for (int k = 0; k < 32; ++k) {
      float a0 = As[ty * 4 + 0][k];
      float a1 = As[ty * 4 + 1][k];
      float a2 = As[ty * 4 + 2][k];
      float a3 = As[ty * 4 + 3][k];
      float4 bv0 = *(const float4*)(&Bs[k][tx * 4]);
      float4 bv1 = *(const float4*)(&Bs[k][64 + tx * 4]);
      float bb[8] = {bv0.x, bv0.y, bv0.z, bv0.w, bv1.x, bv1.y, bv1.z, bv1.w};
      #pragma unroll
      for (int cc = 0; cc < 8; ++cc) {
        acc[0][cc] += a0 * bb[cc];
        acc[1][cc] += a1 * bb[cc];
        acc[2][cc] += a2 * bb[cc];
        acc[3][cc] += a3 * bb[cc];
      }
    }
  }

  float4 bb0 = *(const float4*)(bias + tx * 4);
  float4 bb1 = *(const float4*)(bias + 64 + tx * 4);
  float bb[8] = {bb0.x, bb0.y, bb0.z, bb0.w, bb1.x, bb1.y, bb1.z, bb1.w};
  #pragma unroll
  for (int j = 0; j < 4; ++j) {
    int gr = r0 + ty * 4 + j;
    if (gr < N) {
      float s = RELU_SCALE ? nsrc[gr] : 1.0f;
      float o[8];
      #pragma unroll
      for (int cc = 0; cc < 8; ++cc) {
        float v = acc[j][cc] + bb[cc];
        if (RELU_SCALE) v = fmaxf(v, 0.f) * s;
        o[cc] = v;
      }
      *(float4*)(C + (size_t)gr * D + tx * 4) = make_float4(o[0], o[1], o[2], o[3]);
      *(float4*)(C + (size_t)gr * D + 64 + tx * 4) = make_float4(o[4], o[5], o[6], o[7]);
    }
  }
}

// ---------------- launch ----------------
// ws footprint: esrc 6.4MB + h1s 25.6MB + 4 x 0.2MB = 32.8MB (< round-1's proven
// 33.2MB). psrc/pdst (6.4MB each) alias h1s: dead after scatter_kernel; h1s first
// written by gemm1, strictly later on the same stream.

extern "C" void kernel_launch(void* const* d_in, const int* in_sizes, int n_in,
                              void* d_out, int out_size, void* d_ws, size_t ws_size,
                              hipStream_t stream) {
  const float* feat = (const float*)d_in[0];
  const float* W1   = (const float*)d_in[1];
  const float* b1   = (const float*)d_in[2];
  const float* W2   = (const float*)d_in[3];
  const float* b2   = (const float*)d_in[4];
  const int*   src  = (const int*)d_in[5];
  const int*   dst  = (const int*)d_in[6];
  const int N = in_sizes[0] / D;
  const int E = in_sizes[5];
  float* out = (float*)d_out;

  const int binsR = (N + RANGES - 1) / RANGES;               // 12500
  const int chunkE = (((E + CHUNKS - 1) / CHUNKS) + 3) & ~3; // 50000

  auto align256 = [](size_t x) { return (x + 255) & ~(size_t)255; };
  char* p = (char*)d_ws;
  int*   esrc    = (int*)p;   p += align256((size_t)E * 4);
  float* h1s     = (float*)p; p += align256((size_t)N * D * 4);
  int*   deg_in  = (int*)p;   p += align256((size_t)N * 4);
  int*   row_off = (int*)p;   p += align256((size_t)(N + 1) * 4);
  float* nsrc    = (float*)p; p += align256((size_t)N * 4);
  float* ndst    = (float*)p; p += align256((size_t)N * 4);
  int*   psrc    = (int*)h1s;
  int*   pdst    = (int*)((char*)h1s + align256((size_t)CHUNKS * N * 4));

  hist_kernel<<<RANGES * CHUNKS, 1024, 0, stream>>>(src, psrc, E, N, binsR, chunkE);
  hist_kernel<<<RANGES * CHUNKS, 1024, 0, stream>>>(dst, pdst, E, N, binsR, chunkE);
  reduce_kernel<<<(N + 255) / 256, 256, 0, stream>>>(psrc, pdst, deg_in, nsrc, ndst, N);
  scan_kernel<<<1, 1024, 0, stream>>>(deg_in, row_off, N);
  scatter_kernel<<<RANGES * CHUNKS, 1024, 0, stream>>>(src, dst, pdst, row_off, esrc, E, N, binsR, chunkE);

  // layer 1: agg -> d_out, gemm -> h1s (relu, pre-scaled by nsrc)
  gather_kernel<true><<<(N + 3) / 4, 256, 0, stream>>>(feat, esrc, row_off, nsrc, ndst, out, N);
  gemm128<true><<<(N + 63) / 64, 256, 0, stream>>>(out, W1, b1, nsrc, h1s, N);
  // layer 2: agg -> d_out, gemm in-place on d_out
  gather_kernel<false><<<(N + 3) / 4, 256, 0, stream>>>(h1s, esrc, row_off, nsrc, ndst, out, N);
  gemm128<false><<<(N + 63) / 64, 256, 0, stream>>>(out, W2, b2, nsrc, out, N);
}

// Round 5
// 315.694 us; speedup vs baseline: 1.9050x; 1.4911x over previous
//
#include <hip/hip_runtime.h>

#define D 128
#define RANGES 4
#define CHUNKS 64
#define BINS_MAX 12512   // >= ceil(50000/4)

// ---------------- helpers ----------------

__device__ __forceinline__ unsigned short f2bf(float x) {   // RNE fp32->bf16
  unsigned u = __float_as_uint(x);
  u += 0x7fffu + ((u >> 16) & 1u);
  return (unsigned short)(u >> 16);
}
#define BF_LO(u) __uint_as_float((u) << 16)
#define BF_HI(u) __uint_as_float((u) & 0xffff0000u)

// ---------------- CSR build, stage 1: per-chunk LDS histograms (proven) -------
// block b: r = b&3 (node range), k = b>>2 (edge chunk). Scalar loads.

__global__ __launch_bounds__(1024)
void hist_kernel(const int* __restrict__ keys, int* __restrict__ part,
                 int E, int N, int binsR, int chunkE)
{
  __shared__ int hist[BINS_MAX];
  const int b = blockIdx.x;
  const int r = b & (RANGES - 1);
  const int k = b >> 2;
  const int lo = r * binsR;
  const int hi = min(N, lo + binsR);
  const int nb = hi - lo;
  for (int i = threadIdx.x; i < nb; i += 1024) hist[i] = 0;
  __syncthreads();
  const int e0 = k * chunkE;
  const int e1 = min(E, e0 + chunkE);
  for (int e = e0 + threadIdx.x; e < e1; e += 1024) {
    int v = keys[e];
    if (v >= lo && v < hi) atomicAdd(&hist[v - lo], 1);
  }
  __syncthreads();
  for (int i = threadIdx.x; i < nb; i += 1024) part[(size_t)k * N + lo + i] = hist[i];
}

// per bin: out-deg -> nsrc; in-deg -> ndst, deg_in; pdst -> exclusive prefix over chunks
__global__ void reduce_kernel(const int* __restrict__ psrc, int* __restrict__ pdst,
                              int* __restrict__ deg_in, float* __restrict__ nsrc,
                              float* __restrict__ ndst, int N)
{
  int bin = blockIdx.x * blockDim.x + threadIdx.x;
  if (bin >= N) return;
  int runs = 0, rund = 0;
  for (int k = 0; k < CHUNKS; ++k) {
    runs += psrc[(size_t)k * N + bin];
    int vd = pdst[(size_t)k * N + bin];
    pdst[(size_t)k * N + bin] = rund;
    rund += vd;
  }
  deg_in[bin] = rund;
  nsrc[bin] = rsqrtf((float)runs + 1.0f);   // +1 self-loop
  ndst[bin] = rsqrtf((float)rund + 1.0f);
}

// ---------------- hierarchical exclusive scan: deg_in -> roff[0..N] ----------

__global__ __launch_bounds__(1024)
void scan1_kernel(const int* __restrict__ din, int* __restrict__ roff,
                  int* __restrict__ bsum, int N)
{
  __shared__ int wsum[16];
  const int t = threadIdx.x, lane = t & 63, wid = t >> 6;
  const int i = blockIdx.x * 1024 + t;
  int v = (i < N) ? din[i] : 0;
  int x = v;
  #pragma unroll
  for (int off = 1; off < 64; off <<= 1) {
    int u = __shfl_up(x, off);
    if (lane >= off) x += u;
  }
  if (lane == 63) wsum[wid] = x;            // inclusive wave totals
  __syncthreads();
  if (wid == 0) {
    int y = (lane < 16) ? wsum[lane] : 0;
    int z = y;
    #pragma unroll
    for (int off = 1; off < 16; off <<= 1) {
      int u = __shfl_up(z, off);
      if (lane >= off) z += u;
    }
    if (lane < 16) wsum[lane] = z - y;       // exclusive wave offsets
    if (lane == 15) bsum[blockIdx.x] = z;    // block total
  }
  __syncthreads();
  if (i < N) roff[i] = wsum[wid] + (x - v);  // exclusive within block
}

// single wave scans the (<=64) block totals in-place to exclusive; writes grand total.
__global__ void scan2_kernel(int* __restrict__ bsum, int* __restrict__ roffN, int nb)
{
  const int t = threadIdx.x;  // 64 threads
  int v = (t < nb) ? bsum[t] : 0;
  int x = v;
  #pragma unroll
  for (int off = 1; off < 64; off <<= 1) {
    int u = __shfl_up(x, off);
    if (t >= off) x += u;
  }
  if (t < nb) bsum[t] = x - v;
  if (t == 63) *roffN = x;                   // grand total (tail lanes add 0)
}

__global__ __launch_bounds__(1024)
void scan3_kernel(int* __restrict__ roff, const int* __restrict__ bsum, int N)
{
  const int i = blockIdx.x * 1024 + threadIdx.x;
  if (i < N) roff[i] += bsum[i >> 10];
}

// ---------------- scatter (proven): LDS cursor, deterministic ----------------

__global__ __launch_bounds__(1024)
void scatter_kernel(const int* __restrict__ src, const int* __restrict__ dst,
                    const int* __restrict__ pdst, const int* __restrict__ roff,
                    int* __restrict__ eout, int E, int N, int binsR, int chunkE)
{
  __shared__ int cur[BINS_MAX];
  const int b = blockIdx.x;
  const int r = b & (RANGES - 1);
  const int k = b >> 2;
  const int lo = r * binsR;
  const int hi = min(N, lo + binsR);
  const int nb = hi - lo;
  for (int i = threadIdx.x; i < nb; i += 1024)
    cur[i] = roff[lo + i] + pdst[(size_t)k * N + lo + i];
  __syncthreads();
  const int e0 = k * chunkE;
  const int e1 = min(E, e0 + chunkE);
  for (int e = e0 + threadIdx.x; e < e1; e += 1024) {
    int d = dst[e];
    if (d >= lo && d < hi) eout[atomicAdd(&cur[d - lo], 1)] = src[e];
  }
}

// ---------------- fp32 -> bf16 pack: 4 floats/thread ----------------

__global__ __launch_bounds__(256)
void convert_kernel(const float* __restrict__ f, unsigned* __restrict__ fb, int n4)
{
  const int i = blockIdx.x * blockDim.x + threadIdx.x;
  if (i < n4) {
    float4 v = ((const float4*)f)[i];
    uint2 o;
    o.x = (unsigned)f2bf(v.x) | ((unsigned)f2bf(v.y) << 16);
    o.y = (unsigned)f2bf(v.z) | ((unsigned)f2bf(v.w) << 16);
    ((uint2*)fb)[i] = o;
  }
}

// ---------------- aggregation: bf16 rows, 1 wave/node, uint(bf16x2)/lane ------
// Structure identical to the proven round-1 gather; load type bf16x2, 8-deep MLP.

template<bool SCALE>
__global__ __launch_bounds__(256)
void gather_bf_kernel(const unsigned* __restrict__ fb, const int* __restrict__ eidx,
                      const int* __restrict__ roff, const float* __restrict__ nsrc,
                      const float* __restrict__ ndst, float* __restrict__ out, int N)
{
  const int wid = threadIdx.x >> 6;
  const int lane = threadIdx.x & 63;
  const int node = blockIdx.x * 4 + wid;
  if (node >= N) return;
  unsigned sv = fb[(size_t)node * 64 + lane];
  float sn = SCALE ? nsrc[node] : 1.0f;
  float2 acc = make_float2(BF_LO(sv) * sn, BF_HI(sv) * sn);
  const int beg = roff[node], end = roff[node + 1];
  for (int e0 = beg; e0 < end; e0 += 64) {
    const int cnt = min(64, end - e0);
    int id = (lane < cnt) ? eidx[e0 + lane] : 0;
    int j = 0;
    for (; j + 8 <= cnt; j += 8) {           // 8 independent row-reads in flight
      int s0 = __shfl(id, j + 0), s1 = __shfl(id, j + 1);
      int s2 = __shfl(id, j + 2), s3 = __shfl(id, j + 3);
      int s4 = __shfl(id, j + 4), s5 = __shfl(id, j + 5);
      int s6 = __shfl(id, j + 6), s7 = __shfl(id, j + 7);
      unsigned u0 = fb[(size_t)s0 * 64 + lane];
      unsigned u1 = fb[(size_t)s1 * 64 + lane];
      unsigned u2 = fb[(size_t)s2 * 64 + lane];
      unsigned u3 = fb[(size_t)s3 * 64 + lane];
      unsigned u4 = fb[(size_t)s4 * 64 + lane];
      unsigned u5 = fb[(size_t)s5 * 64 + lane];
      unsigned u6 = fb[(size_t)s6 * 64 + lane];
      unsigned u7 = fb[(size_t)s7 * 64 + lane];
      float n0 = SCALE ? nsrc[s0] : 1.0f, n1 = SCALE ? nsrc[s1] : 1.0f;
      float n2 = SCALE ? nsrc[s2] : 1.0f, n3 = SCALE ? nsrc[s3] : 1.0f;
      float n4 = SCALE ? nsrc[s4] : 1.0f, n5 = SCALE ? nsrc[s5] : 1.0f;
      float n6 = SCALE ? nsrc[s6] : 1.0f, n7 = SCALE ? nsrc[s7] : 1.0f;
      acc.x += BF_LO(u0) * n0; acc.y += BF_HI(u0) * n0;
      acc.x += BF_LO(u1) * n1; acc.y += BF_HI(u1) * n1;
      acc.x += BF_LO(u2) * n2; acc.y += BF_HI(u2) * n2;
      acc.x += BF_LO(u3) * n3; acc.y += BF_HI(u3) * n3;
      acc.x += BF_LO(u4) * n4; acc.y += BF_HI(u4) * n4;
      acc.x += BF_LO(u5) * n5; acc.y += BF_HI(u5) * n5;
      acc.x += BF_LO(u6) * n6; acc.y += BF_HI(u6) * n6;
      acc.x += BF_LO(u7) * n7; acc.y += BF_HI(u7) * n7;
    }
    for (; j < cnt; ++j) {
      int s = __shfl(id, j);
      unsigned u = fb[(size_t)s * 64 + lane];
      float n = SCALE ? nsrc[s] : 1.0f;
      acc.x += BF_LO(u) * n; acc.y += BF_HI(u) * n;
    }
  }
  float nd = ndst[node];
  acc.x *= nd; acc.y *= nd;
  *(float2*)(out + (size_t)node * D + lane * 2) = acc;
}

// ---------------- fp32 GEMM (proven), epilogue optionally stores bf16 --------

template<bool RELU_SCALE, bool BF_OUT>
__global__ __launch_bounds__(256)
void gemm128(const float* __restrict__ A, const float* __restrict__ W,
             const float* __restrict__ bias, const float* __restrict__ nsrc,
             void* __restrict__ Cv, int N)
{
  __shared__ float As[64][36];
  __shared__ float Bs[32][128];
  const int t = threadIdx.x;
  const int tx = t & 15;
  const int ty = t >> 4;
  const int r0 = blockIdx.x * 64;
  float acc[4][8];
  #pragma unroll
  for (int j = 0; j < 4; ++j)
    #pragma unroll
    for (int cc = 0; cc < 8; ++cc) acc[j][cc] = 0.f;

  for (int kc = 0; kc < D; kc += 32) {
    __syncthreads();
    #pragma unroll
    for (int m = 0; m < 2; ++m) {
      int q = t * 2 + m;
      int row = q >> 3;
      int fc = q & 7;
      int gr = r0 + row; if (gr > N - 1) gr = N - 1;
      float4 v = *(const float4*)(A + (size_t)gr * D + kc + fc * 4);
      *(float4*)(&As[row][fc * 4]) = v;
    }
    #pragma unroll
    for (int m = 0; m < 4; ++m) {
      int q = t + 256 * m;
      int kk = q >> 5;
      int fc = q & 31;
      float4 v = *(const float4*)(W + (size_t)(kc + kk) * D + fc * 4);
      *(float4*)(&Bs[kk][fc * 4]) = v;
    }
    __syncthreads();
    #pragma unroll
    for (int k = 0; k < 32; ++k) {
      float a0 = As[ty * 4 + 0][k];
      float a1 = As[ty * 4 + 1][k];
      float a2 = As[ty * 4 + 2][k];
      float a3 = As[ty * 4 + 3][k];
      float4 bv0 = *(const float4*)(&Bs[k][tx * 4]);
      float4 bv1 = *(const float4*)(&Bs[k][64 + tx * 4]);
      float bb[8] = {bv0.x, bv0.y, bv0.z, bv0.w, bv1.x, bv1.y, bv1.z, bv1.w};
      #pragma unroll
      for (int cc = 0; cc < 8; ++cc) {
        acc[0][cc] += a0 * bb[cc];
        acc[1][cc] += a1 * bb[cc];
        acc[2][cc] += a2 * bb[cc];
        acc[3][cc] += a3 * bb[cc];
      }
    }
  }

  float4 bb0 = *(const float4*)(bias + tx * 4);
  float4 bb1 = *(const float4*)(bias + 64 + tx * 4);
  float bb[8] = {bb0.x, bb0.y, bb0.z, bb0.w, bb1.x, bb1.y, bb1.z, bb1.w};
  #pragma unroll
  for (int j = 0; j < 4; ++j) {
    int gr = r0 + ty * 4 + j;
    if (gr < N) {
      float s = RELU_SCALE ? nsrc[gr] : 1.0f;
      float o[8];
      #pragma unroll
      for (int cc = 0; cc < 8; ++cc) {
        float v = acc[j][cc] + bb[cc];
        if (RELU_SCALE) v = fmaxf(v, 0.f) * s;
        o[cc] = v;
      }
      if (BF_OUT) {
        unsigned short* Cb = (unsigned short*)Cv;
        ushort4 w0, w1;
        w0.x = f2bf(o[0]); w0.y = f2bf(o[1]); w0.z = f2bf(o[2]); w0.w = f2bf(o[3]);
        w1.x = f2bf(o[4]); w1.y = f2bf(o[5]); w1.z = f2bf(o[6]); w1.w = f2bf(o[7]);
        *(ushort4*)(Cb + (size_t)gr * D + tx * 4) = w0;
        *(ushort4*)(Cb + (size_t)gr * D + 64 + tx * 4) = w1;
      } else {
        float* C = (float*)Cv;
        *(float4*)(C + (size_t)gr * D + tx * 4) = make_float4(o[0], o[1], o[2], o[3]);
        *(float4*)(C + (size_t)gr * D + 64 + tx * 4) = make_float4(o[4], o[5], o[6], o[7]);
      }
    }
  }
}

// ---------------- launch ----------------
// ws: esrc 6.4MB | big 25.6MB | smalls ~0.8MB = 32.8MB (<= proven 33.2MB).
// big region aliases: psrc=[0:12.8M] (dies after reduce) -> featbf=[0:12.8M]
// (written by convert AFTER reduce, read by gather1);
// pdst=[12.8:25.6M] (dies after scatter) -> h1bf=[12.8:25.6M] (written by gemm1
// AFTER gather1 > after scatter, read by gather2). Same-stream ordering.

extern "C" void kernel_launch(void* const* d_in, const int* in_sizes, int n_in,
                              void* d_out, int out_size, void* d_ws, size_t ws_size,
                              hipStream_t stream) {
  const float* feat = (const float*)d_in[0];
  const float* W1   = (const float*)d_in[1];
  const float* b1   = (const float*)d_in[2];
  const float* W2   = (const float*)d_in[3];
  const float* b2   = (const float*)d_in[4];
  const int*   src  = (const int*)d_in[5];
  const int*   dst  = (const int*)d_in[6];
  const int N = in_sizes[0] / D;
  const int E = in_sizes[5];
  float* out = (float*)d_out;

  const int binsR = (N + RANGES - 1) / RANGES;               // 12500
  const int chunkE = (((E + CHUNKS - 1) / CHUNKS) + 3) & ~3; // 25000

  auto align256 = [](size_t x) { return (x + 255) & ~(size_t)255; };
  char* p = (char*)d_ws;
  int*   esrc    = (int*)p;   p += align256((size_t)E * 4);
  char*  big     = p;         p += 2 * align256((size_t)CHUNKS * N * 4);
  int*   deg_in  = (int*)p;   p += align256((size_t)N * 4);
  int*   row_off = (int*)p;   p += align256((size_t)(N + 1) * 4);
  float* nsrc    = (float*)p; p += align256((size_t)N * 4);
  float* ndst    = (float*)p; p += align256((size_t)N * 4);
  int*   bsum    = (int*)p;   p += 256;
  int*      psrc   = (int*)big;
  int*      pdst   = (int*)(big + align256((size_t)CHUNKS * N * 4));
  unsigned* featbf = (unsigned*)psrc;         // alias, after reduce
  unsigned* h1bf   = (unsigned*)pdst;         // alias, after scatter

  const int nblk = (N + 1023) / 1024;         // 49 (<= 64 required by scan2)

  hist_kernel<<<RANGES * CHUNKS, 1024, 0, stream>>>(src, psrc, E, N, binsR, chunkE);
  hist_kernel<<<RANGES * CHUNKS, 1024, 0, stream>>>(dst, pdst, E, N, binsR, chunkE);
  reduce_kernel<<<(N + 255) / 256, 256, 0, stream>>>(psrc, pdst, deg_in, nsrc, ndst, N);
  convert_kernel<<<(N * D / 4 + 255) / 256, 256, 0, stream>>>(feat, featbf, N * D / 4);
  scan1_kernel<<<nblk, 1024, 0, stream>>>(deg_in, row_off, bsum, N);
  scan2_kernel<<<1, 64, 0, stream>>>(bsum, row_off + N, nblk);
  scan3_kernel<<<nblk, 1024, 0, stream>>>(row_off, bsum, N);
  scatter_kernel<<<RANGES * CHUNKS, 1024, 0, stream>>>(src, dst, pdst, row_off, esrc, E, N, binsR, chunkE);

  // layer 1: agg(bf16 feat) -> d_out (fp32), gemm -> h1bf (bf16, relu, *nsrc)
  gather_bf_kernel<true><<<(N + 3) / 4, 256, 0, stream>>>(featbf, esrc, row_off, nsrc, ndst, out, N);
  gemm128<true, true><<<(N + 63) / 64, 256, 0, stream>>>(out, W1, b1, nsrc, h1bf, N);
  // layer 2: agg(bf16 h1) -> d_out (fp32), gemm in-place fp32
  gather_bf_kernel<false><<<(N + 3) / 4, 256, 0, stream>>>(h1bf, esrc, row_off, nsrc, ndst, out, N);
  gemm128<false, false><<<(N + 63) / 64, 256, 0, stream>>>(out, W2, b2, nsrc, out, N);
}

// Round 7
// 314.393 us; speedup vs baseline: 1.9128x; 1.0041x over previous
//
#include <hip/hip_runtime.h>

#define D 128
#define RANGES 4
#define CHUNKS 64
#define BINS_MAX 12512   // >= ceil(50000/4)

typedef unsigned short u16;

// ---------------- helpers ----------------

__device__ __forceinline__ u16 f2bf(float x) {   // RNE fp32->bf16
  unsigned u = __float_as_uint(x);
  u += 0x7fffu + ((u >> 16) & 1u);
  return (u16)(u >> 16);
}
#define BF_LO(u) __uint_as_float((u) << 16)
#define BF_HI(u) __uint_as_float((u) & 0xffff0000u)

// ---------------- CSR build, stage 1: per-chunk LDS histograms (proven) -------
// block b: r = b&3 (node range), k = b>>2 (edge chunk). Scalar loads.
// Partial counts stored as ushort (max per chunk-bin <= chunkE=25000 < 2^16).

__global__ __launch_bounds__(1024)
void hist_kernel(const int* __restrict__ keys, u16* __restrict__ part,
                 int E, int N, int binsR, int chunkE)
{
  __shared__ int hist[BINS_MAX];
  const int b = blockIdx.x;
  const int r = b & (RANGES - 1);
  const int k = b >> 2;
  const int lo = r * binsR;
  const int hi = min(N, lo + binsR);
  const int nb = hi - lo;
  for (int i = threadIdx.x; i < nb; i += 1024) hist[i] = 0;
  __syncthreads();
  const int e0 = k * chunkE;
  const int e1 = min(E, e0 + chunkE);
  for (int e = e0 + threadIdx.x; e < e1; e += 1024) {
    int v = keys[e];
    if (v >= lo && v < hi) atomicAdd(&hist[v - lo], 1);
  }
  __syncthreads();
  for (int i = threadIdx.x; i < nb; i += 1024)
    part[(size_t)k * N + lo + i] = (u16)hist[i];
}

// per bin: out-deg -> nsrc; in-deg -> ndst, deg_in; pdst -> exclusive prefix over
// chunks (prefix <= in-degree of the bin, tiny; fits ushort).
__global__ void reduce_kernel(const u16* __restrict__ psrc, u16* __restrict__ pdst,
                              int* __restrict__ deg_in, float* __restrict__ nsrc,
                              float* __restrict__ ndst, int N)
{
  int bin = blockIdx.x * blockDim.x + threadIdx.x;
  if (bin >= N) return;
  int runs = 0, rund = 0;
  for (int k = 0; k < CHUNKS; ++k) {
    runs += psrc[(size_t)k * N + bin];
    int vd = pdst[(size_t)k * N + bin];
    pdst[(size_t)k * N + bin] = (u16)rund;
    rund += vd;
  }
  deg_in[bin] = rund;
  nsrc[bin] = rsqrtf((float)runs + 1.0f);   // +1 self-loop
  ndst[bin] = rsqrtf((float)rund + 1.0f);
}

// ---------------- hierarchical exclusive scan (proven): deg_in -> roff --------

__global__ __launch_bounds__(1024)
void scan1_kernel(const int* __restrict__ din, int* __restrict__ roff,
                  int* __restrict__ bsum, int N)
{
  __shared__ int wsum[16];
  const int t = threadIdx.x, lane = t & 63, wid = t >> 6;
  const int i = blockIdx.x * 1024 + t;
  int v = (i < N) ? din[i] : 0;
  int x = v;
  #pragma unroll
  for (int off = 1; off < 64; off <<= 1) {
    int u = __shfl_up(x, off);
    if (lane >= off) x += u;
  }
  if (lane == 63) wsum[wid] = x;
  __syncthreads();
  if (wid == 0) {
    int y = (lane < 16) ? wsum[lane] : 0;
    int z = y;
    #pragma unroll
    for (int off = 1; off < 16; off <<= 1) {
      int u = __shfl_up(z, off);
      if (lane >= off) z += u;
    }
    if (lane < 16) wsum[lane] = z - y;
    if (lane == 15) bsum[blockIdx.x] = z;
  }
  __syncthreads();
  if (i < N) roff[i] = wsum[wid] + (x - v);
}

__global__ void scan2_kernel(int* __restrict__ bsum, int* __restrict__ roffN, int nb)
{
  const int t = threadIdx.x;  // 64 threads
  int v = (t < nb) ? bsum[t] : 0;
  int x = v;
  #pragma unroll
  for (int off = 1; off < 64; off <<= 1) {
    int u = __shfl_up(x, off);
    if (t >= off) x += u;
  }
  if (t < nb) bsum[t] = x - v;
  if (t == 63) *roffN = x;
}

__global__ __launch_bounds__(1024)
void scan3_kernel(int* __restrict__ roff, const int* __restrict__ bsum, int N)
{
  const int i = blockIdx.x * 1024 + threadIdx.x;
  if (i < N) roff[i] += bsum[i >> 10];
}

// ---------------- scatter (proven): LDS cursor, deterministic ----------------

__global__ __launch_bounds__(1024)
void scatter_kernel(const int* __restrict__ src, const int* __restrict__ dst,
                    const u16* __restrict__ pdst, const int* __restrict__ roff,
                    int* __restrict__ eout, int E, int N, int binsR, int chunkE)
{
  __shared__ int cur[BINS_MAX];
  const int b = blockIdx.x;
  const int r = b & (RANGES - 1);
  const int k = b >> 2;
  const int lo = r * binsR;
  const int hi = min(N, lo + binsR);
  const int nb = hi - lo;
  for (int i = threadIdx.x; i < nb; i += 1024)
    cur[i] = roff[lo + i] + (int)pdst[(size_t)k * N + lo + i];
  __syncthreads();
  const int e0 = k * chunkE;
  const int e1 = min(E, e0 + chunkE);
  for (int e = e0 + threadIdx.x; e < e1; e += 1024) {
    int d = dst[e];
    if (d >= lo && d < hi) eout[atomicAdd(&cur[d - lo], 1)] = src[e];
  }
}

// ---------------- fp32 -> bf16 pack, pre-scaled by nsrc[row] ----------------
// float4 index i covers elements 4i..4i+3, all in node i>>5 (row = 128 floats).

__global__ __launch_bounds__(256)
void convert_kernel(const float* __restrict__ f, const float* __restrict__ nsrc,
                    unsigned* __restrict__ fb, int n4)
{
  const int i = blockIdx.x * blockDim.x + threadIdx.x;
  if (i < n4) {
    float s = nsrc[i >> 5];
    float4 v = ((const float4*)f)[i];
    uint2 o;
    o.x = (unsigned)f2bf(v.x * s) | ((unsigned)f2bf(v.y * s) << 16);
    o.y = (unsigned)f2bf(v.z * s) | ((unsigned)f2bf(v.w * s) << 16);
    ((uint2*)fb)[i] = o;
  }
}

// ---------------- aggregation: bf16 rows, 1 wave/node, half-wave per edge ----
// Input rows are pre-scaled (featbf by convert; h1bf by gemm1 epilogue).
// Lane = (h, q): half h handles edges 2u+h; q indexes uint2 (dims 4q..4q+3).
// CRITICAL (root cause of rounds 2/3/6 failures): every __shfl must execute
// with ALL 64 lanes active — ds_bpermute latches only EXEC-active source
// lanes, so a shfl inside a divergent guard reading from the masked-off half
// returns garbage/0. Shuffles below are unconditional; only loads/accumulates
// are guarded.

__global__ __launch_bounds__(256)
void gather_bf_kernel(const unsigned* __restrict__ fb, const int* __restrict__ eidx,
                      const int* __restrict__ roff, const float* __restrict__ ndst,
                      float* __restrict__ out, int N)
{
  const int wid = threadIdx.x >> 6;
  const int lane = threadIdx.x & 63;
  const int node = blockIdx.x * 4 + wid;
  if (node >= N) return;                 // wave-uniform (node is per-wave)
  const int h = lane >> 5;
  const int q = lane & 31;
  const uint2* fb2 = (const uint2*)fb;
  float4 acc = make_float4(0.f, 0.f, 0.f, 0.f);
  if (h == 0) {                          // self term (pre-scaled row)
    uint2 u = fb2[(size_t)node * 32 + q];
    acc.x = BF_LO(u.x); acc.y = BF_HI(u.x);
    acc.z = BF_LO(u.y); acc.w = BF_HI(u.y);
  }
  const int beg = roff[node], end = roff[node + 1];
  for (int e0 = beg; e0 < end; e0 += 64) {
    const int cnt = min(64, end - e0);   // wave-uniform
    int id = (lane < cnt) ? eidx[e0 + lane] : 0;
    int j = 0;
    for (; j + 16 <= cnt; j += 16) {     // 8 row-reads in flight per half-wave
      int s0 = __shfl(id, j + 0 + h);    // all lanes active, indices < cnt
      int s1 = __shfl(id, j + 2 + h);
      int s2 = __shfl(id, j + 4 + h);
      int s3 = __shfl(id, j + 6 + h);
      int s4 = __shfl(id, j + 8 + h);
      int s5 = __shfl(id, j + 10 + h);
      int s6 = __shfl(id, j + 12 + h);
      int s7 = __shfl(id, j + 14 + h);
      uint2 u0 = fb2[(size_t)s0 * 32 + q];
      uint2 u1 = fb2[(size_t)s1 * 32 + q];
      uint2 u2 = fb2[(size_t)s2 * 32 + q];
      uint2 u3 = fb2[(size_t)s3 * 32 + q];
      uint2 u4 = fb2[(size_t)s4 * 32 + q];
      uint2 u5 = fb2[(size_t)s5 * 32 + q];
      uint2 u6 = fb2[(size_t)s6 * 32 + q];
      uint2 u7 = fb2[(size_t)s7 * 32 + q];
      acc.x += BF_LO(u0.x); acc.y += BF_HI(u0.x); acc.z += BF_LO(u0.y); acc.w += BF_HI(u0.y);
      acc.x += BF_LO(u1.x); acc.y += BF_HI(u1.x); acc.z += BF_LO(u1.y); acc.w += BF_HI(u1.y);
      acc.x += BF_LO(u2.x); acc.y += BF_HI(u2.x); acc.z += BF_LO(u2.y); acc.w += BF_HI(u2.y);
      acc.x += BF_LO(u3.x); acc.y += BF_HI(u3.x); acc.z += BF_LO(u3.y); acc.w += BF_HI(u3.y);
      acc.x += BF_LO(u4.x); acc.y += BF_HI(u4.x); acc.z += BF_LO(u4.y); acc.w += BF_HI(u4.y);
      acc.x += BF_LO(u5.x); acc.y += BF_HI(u5.x); acc.z += BF_LO(u5.y); acc.w += BF_HI(u5.y);
      acc.x += BF_LO(u6.x); acc.y += BF_HI(u6.x); acc.z += BF_LO(u6.y); acc.w += BF_HI(u6.y);
      acc.x += BF_LO(u7.x); acc.y += BF_HI(u7.x); acc.z += BF_LO(u7.y); acc.w += BF_HI(u7.y);
    }
    for (; j < cnt; j += 2) {            // tail: shfl UNCONDITIONAL, load guarded
      int ej = j + h;
      int s = __shfl(id, ej & 63);       // ej==64 masks to 0; result unused then
      if (ej < cnt) {
        uint2 u = fb2[(size_t)s * 32 + q];
        acc.x += BF_LO(u.x); acc.y += BF_HI(u.x);
        acc.z += BF_LO(u.y); acc.w += BF_HI(u.y);
      }
    }
  }
  acc.x += __shfl_xor(acc.x, 32);
  acc.y += __shfl_xor(acc.y, 32);
  acc.z += __shfl_xor(acc.z, 32);
  acc.w += __shfl_xor(acc.w, 32);
  if (h == 0) {
    float nd = ndst[node];
    acc.x *= nd; acc.y *= nd; acc.z *= nd; acc.w *= nd;
    *(float4*)(out + (size_t)node * D + q * 4) = acc;
  }
}

// ---------------- fp32 GEMM (proven), epilogue optionally stores bf16 --------

template<bool RELU_SCALE, bool BF_OUT>
__global__ __launch_bounds__(256)
void gemm128(const float* __restrict__ A, const float* __restrict__ W,
             const float* __restrict__ bias, const float* __restrict__ nsrc,
             void* __restrict__ Cv, int N)
{
  __shared__ float As[64][36];
  __shared__ float Bs[32][128];
  const int t = threadIdx.x;
  const int tx = t & 15;
  const int ty = t >> 4;
  const int r0 = blockIdx.x * 64;
  float acc[4][8];
  #pragma unroll
  for (int j = 0; j < 4; ++j)
    #pragma unroll
    for (int cc = 0; cc < 8; ++cc) acc[j][cc] = 0.f;

  for (int kc = 0; kc < D; kc += 32) {
    __syncthreads();
    #pragma unroll
    for (int m = 0; m < 2; ++m) {
      int q = t * 2 + m;
      int row = q >> 3;
      int fc = q & 7;
      int gr = r0 + row; if (gr > N - 1) gr = N - 1;
      float4 v = *(const float4*)(A + (size_t)gr * D + kc + fc * 4);
      *(float4*)(&As[row][fc * 4]) = v;
    }
    #pragma unroll
    for (int m = 0; m < 4; ++m) {
      int q = t + 256 * m;
      int kk = q >> 5;
      int fc = q & 31;
      float4 v = *(const float4*)(W + (size_t)(kc + kk) * D + fc * 4);
      *(float4*)(&Bs[kk][fc * 4]) = v;
    }
    __syncthreads();
    #pragma unroll
    for (int k = 0; k < 32; ++k) {
      float a0 = As[ty * 4 + 0][k];
      float a1 = As[ty * 4 + 1][k];
      float a2 = As[ty * 4 + 2][k];
      float a3 = As[ty * 4 + 3][k];
      float4 bv0 = *(const float4*)(&Bs[k][tx * 4]);
      float4 bv1 = *(const float4*)(&Bs[k][64 + tx * 4]);
      float bb[8] = {bv0.x, bv0.y, bv0.z, bv0.w, bv1.x, bv1.y, bv1.z, bv1.w};
      #pragma unroll
      for (int cc = 0; cc < 8; ++cc) {
        acc[0][cc] += a0 * bb[cc];
        acc[1][cc] += a1 * bb[cc];
        acc[2][cc] += a2 * bb[cc];
        acc[3][cc] += a3 * bb[cc];
      }
    }
  }

  float4 bb0 = *(const float4*)(bias + tx * 4);
  float4 bb1 = *(const float4*)(bias + 64 + tx * 4);
  float bb[8] = {bb0.x, bb0.y, bb0.z, bb0.w, bb1.x, bb1.y, bb1.z, bb1.w};
  #pragma unroll
  for (int j = 0; j < 4; ++j) {
    int gr = r0 + ty * 4 + j;
    if (gr < N) {
      float s = RELU_SCALE ? nsrc[gr] : 1.0f;
      float o[8];
      #pragma unroll
      for (int cc = 0; cc < 8; ++cc) {
        float v = acc[j][cc] + bb[cc];
        if (RELU_SCALE) v = fmaxf(v, 0.f) * s;
        o[cc] = v;
      }
      if (BF_OUT) {
        u16* Cb = (u16*)Cv;
        ushort4 w0, w1;
        w0.x = f2bf(o[0]); w0.y = f2bf(o[1]); w0.z = f2bf(o[2]); w0.w = f2bf(o[3]);
        w1.x = f2bf(o[4]); w1.y = f2bf(o[5]); w1.z = f2bf(o[6]); w1.w = f2bf(o[7]);
        *(ushort4*)(Cb + (size_t)gr * D + tx * 4) = w0;
        *(ushort4*)(Cb + (size_t)gr * D + 64 + tx * 4) = w1;
      } else {
        float* C = (float*)Cv;
        *(float4*)(C + (size_t)gr * D + tx * 4) = make_float4(o[0], o[1], o[2], o[3]);
        *(float4*)(C + (size_t)gr * D + 64 + tx * 4) = make_float4(o[4], o[5], o[6], o[7]);
      }
    }
  }
}

// ---------------- launch ----------------
// ws layout (32.8MB <= proven 33.2MB), lifetime-disjoint aliases on one stream:
//   p0 [6.4MB]:  psrc (hist1..reduce) -> esrc (scatter..gather2)
//   p1 [12.8MB]: pdst in first 6.4MB (hist2..scatter) -> h1bf full (gemm1..gather2)
//   p2 [12.8MB]: featbf (convert..gather1)
//   smalls: deg_in, row_off, nsrc, ndst, bsum

extern "C" void kernel_launch(void* const* d_in, const int* in_sizes, int n_in,
                              void* d_out, int out_size, void* d_ws, size_t ws_size,
                              hipStream_t stream) {
  const float* feat = (const float*)d_in[0];
  const float* W1   = (const float*)d_in[1];
  const float* b1   = (const float*)d_in[2];
  const float* W2   = (const float*)d_in[3];
  const float* b2   = (const float*)d_in[4];
  const int*   src  = (const int*)d_in[5];
  const int*   dst  = (const int*)d_in[6];
  const int N = in_sizes[0] / D;
  const int E = in_sizes[5];
  float* out = (float*)d_out;

  const int binsR = (N + RANGES - 1) / RANGES;               // 12500
  const int chunkE = (((E + CHUNKS - 1) / CHUNKS) + 3) & ~3; // 25000

  auto align256 = [](size_t x) { return (x + 255) & ~(size_t)255; };
  char* p = (char*)d_ws;
  char* p0 = p;  p += align256((size_t)E * 4);               // 6.4 MB
  char* p1 = p;  p += align256((size_t)N * D * 2);           // 12.8 MB
  char* p2 = p;  p += align256((size_t)N * D * 2);           // 12.8 MB
  int*   deg_in  = (int*)p;   p += align256((size_t)N * 4);
  int*   row_off = (int*)p;   p += align256((size_t)(N + 1) * 4);
  float* nsrc    = (float*)p; p += align256((size_t)N * 4);
  float* ndst    = (float*)p; p += align256((size_t)N * 4);
  int*   bsum    = (int*)p;   p += 256;

  u16*      psrc   = (u16*)p0;      // dies after reduce
  int*      esrc   = (int*)p0;      // written by scatter
  u16*      pdst   = (u16*)p1;      // dies after scatter
  u16*      h1bf   = (u16*)p1;      // written by gemm1
  unsigned* featbf = (unsigned*)p2;

  const int nblk = (N + 1023) / 1024;   // 49 (<= 64 for scan2)

  hist_kernel<<<RANGES * CHUNKS, 1024, 0, stream>>>(src, psrc, E, N, binsR, chunkE);
  hist_kernel<<<RANGES * CHUNKS, 1024, 0, stream>>>(dst, pdst, E, N, binsR, chunkE);
  reduce_kernel<<<(N + 255) / 256, 256, 0, stream>>>(psrc, pdst, deg_in, nsrc, ndst, N);
  convert_kernel<<<(N * D / 4 + 255) / 256, 256, 0, stream>>>(feat, nsrc, featbf, N * D / 4);
  scan1_kernel<<<nblk, 1024, 0, stream>>>(deg_in, row_off, bsum, N);
  scan2_kernel<<<1, 64, 0, stream>>>(bsum, row_off + N, nblk);
  scan3_kernel<<<nblk, 1024, 0, stream>>>(row_off, bsum, N);
  scatter_kernel<<<RANGES * CHUNKS, 1024, 0, stream>>>(src, dst, pdst, row_off, esrc, E, N, binsR, chunkE);

  // layer 1: agg(pre-scaled bf16 feat) -> d_out (fp32), gemm -> h1bf (bf16, relu*nsrc)
  gather_bf_kernel<<<(N + 3) / 4, 256, 0, stream>>>(featbf, esrc, row_off, ndst, out, N);
  gemm128<true, true><<<(N + 63) / 64, 256, 0, stream>>>(out, W1, b1, nsrc, h1bf, N);
  // layer 2: agg(pre-scaled bf16 h1) -> d_out (fp32), gemm in-place fp32
  gather_bf_kernel<<<(N + 3) / 4, 256, 0, stream>>>((const unsigned*)h1bf, esrc, row_off, ndst, out, N);
  gemm128<false, false><<<(N + 63) / 64, 256, 0, stream>>>(out, W2, b2, nsrc, out, N);
}

// Round 8
// 306.472 us; speedup vs baseline: 1.9623x; 1.0258x over previous
//
#include <hip/hip_runtime.h>

#define D 128
#define RANGES 4
#define CHUNKS 64
#define BINS_MAX 12512   // >= ceil(50000/4)

typedef unsigned short u16;

// ---------------- helpers ----------------

__device__ __forceinline__ u16 f2bf(float x) {   // RNE fp32->bf16
  unsigned u = __float_as_uint(x);
  u += 0x7fffu + ((u >> 16) & 1u);
  return (u16)(u >> 16);
}
#define BF_LO(u) __uint_as_float((u) << 16)
#define BF_HI(u) __uint_as_float((u) & 0xffff0000u)

// ---------------- CSR build, stage 1: per-chunk LDS histograms (proven) -------

__global__ __launch_bounds__(1024)
void hist_kernel(const int* __restrict__ keys, u16* __restrict__ part,
                 int E, int N, int binsR, int chunkE)
{
  __shared__ int hist[BINS_MAX];
  const int b = blockIdx.x;
  const int r = b & (RANGES - 1);
  const int k = b >> 2;
  const int lo = r * binsR;
  const int hi = min(N, lo + binsR);
  const int nb = hi - lo;
  for (int i = threadIdx.x; i < nb; i += 1024) hist[i] = 0;
  __syncthreads();
  const int e0 = k * chunkE;
  const int e1 = min(E, e0 + chunkE);
  for (int e = e0 + threadIdx.x; e < e1; e += 1024) {
    int v = keys[e];
    if (v >= lo && v < hi) atomicAdd(&hist[v - lo], 1);
  }
  __syncthreads();
  for (int i = threadIdx.x; i < nb; i += 1024)
    part[(size_t)k * N + lo + i] = (u16)hist[i];
}

// per bin: out-deg -> nsrc; in-deg -> ndst, deg_in; pdst -> exclusive prefix over chunks
__global__ void reduce_kernel(const u16* __restrict__ psrc, u16* __restrict__ pdst,
                              int* __restrict__ deg_in, float* __restrict__ nsrc,
                              float* __restrict__ ndst, int N)
{
  int bin = blockIdx.x * blockDim.x + threadIdx.x;
  if (bin >= N) return;
  int runs = 0, rund = 0;
  for (int k = 0; k < CHUNKS; ++k) {
    runs += psrc[(size_t)k * N + bin];
    int vd = pdst[(size_t)k * N + bin];
    pdst[(size_t)k * N + bin] = (u16)rund;
    rund += vd;
  }
  deg_in[bin] = rund;
  nsrc[bin] = rsqrtf((float)runs + 1.0f);   // +1 self-loop
  ndst[bin] = rsqrtf((float)rund + 1.0f);
}

// ---------------- hierarchical exclusive scan (proven): deg_in -> roff --------

__global__ __launch_bounds__(1024)
void scan1_kernel(const int* __restrict__ din, int* __restrict__ roff,
                  int* __restrict__ bsum, int N)
{
  __shared__ int wsum[16];
  const int t = threadIdx.x, lane = t & 63, wid = t >> 6;
  const int i = blockIdx.x * 1024 + t;
  int v = (i < N) ? din[i] : 0;
  int x = v;
  #pragma unroll
  for (int off = 1; off < 64; off <<= 1) {
    int u = __shfl_up(x, off);
    if (lane >= off) x += u;
  }
  if (lane == 63) wsum[wid] = x;
  __syncthreads();
  if (wid == 0) {
    int y = (lane < 16) ? wsum[lane] : 0;
    int z = y;
    #pragma unroll
    for (int off = 1; off < 16; off <<= 1) {
      int u = __shfl_up(z, off);
      if (lane >= off) z += u;
    }
    if (lane < 16) wsum[lane] = z - y;
    if (lane == 15) bsum[blockIdx.x] = z;
  }
  __syncthreads();
  if (i < N) roff[i] = wsum[wid] + (x - v);
}

__global__ void scan2_kernel(int* __restrict__ bsum, int* __restrict__ roffN, int nb)
{
  const int t = threadIdx.x;  // 64 threads
  int v = (t < nb) ? bsum[t] : 0;
  int x = v;
  #pragma unroll
  for (int off = 1; off < 64; off <<= 1) {
    int u = __shfl_up(x, off);
    if (t >= off) x += u;
  }
  if (t < nb) bsum[t] = x - v;
  if (t == 63) *roffN = x;
}

__global__ __launch_bounds__(1024)
void scan3_kernel(int* __restrict__ roff, const int* __restrict__ bsum, int N)
{
  const int i = blockIdx.x * 1024 + threadIdx.x;
  if (i < N) roff[i] += bsum[i >> 10];
}

// ---------------- scatter (proven structure): LDS cursor; u16 edge values ----

__global__ __launch_bounds__(1024)
void scatter_kernel(const int* __restrict__ src, const int* __restrict__ dst,
                    const u16* __restrict__ pdst, const int* __restrict__ roff,
                    u16* __restrict__ eout, int E, int N, int binsR, int chunkE)
{
  __shared__ int cur[BINS_MAX];
  const int b = blockIdx.x;
  const int r = b & (RANGES - 1);
  const int k = b >> 2;
  const int lo = r * binsR;
  const int hi = min(N, lo + binsR);
  const int nb = hi - lo;
  for (int i = threadIdx.x; i < nb; i += 1024)
    cur[i] = roff[lo + i] + (int)pdst[(size_t)k * N + lo + i];
  __syncthreads();
  const int e0 = k * chunkE;
  const int e1 = min(E, e0 + chunkE);
  for (int e = e0 + threadIdx.x; e < e1; e += 1024) {
    int d = dst[e];
    if (d >= lo && d < hi) eout[atomicAdd(&cur[d - lo], 1)] = (u16)src[e];
  }
}

// ---------------- fp32 -> bf16 pack, pre-scaled by nsrc[row] (proven) --------

__global__ __launch_bounds__(256)
void convert_kernel(const float* __restrict__ f, const float* __restrict__ nsrc,
                    unsigned* __restrict__ fb, int n4)
{
  const int i = blockIdx.x * blockDim.x + threadIdx.x;
  if (i < n4) {
    float s = nsrc[i >> 5];
    float4 v = ((const float4*)f)[i];
    uint2 o;
    o.x = (unsigned)f2bf(v.x * s) | ((unsigned)f2bf(v.y * s) << 16);
    o.y = (unsigned)f2bf(v.z * s) | ((unsigned)f2bf(v.w * s) << 16);
    ((uint2*)fb)[i] = o;
  }
}

// ---------------- aggregation (proven structure): bf16 rows, half-wave/edge --
// Outputs bf16 rows (ushort4 per lane q). u16 edge indices.
// CRITICAL: all __shfl execute with 64 lanes active (rounds 2/3/6 root cause).

__global__ __launch_bounds__(256)
void gather_bf_kernel(const unsigned* __restrict__ fb, const u16* __restrict__ eidx,
                      const int* __restrict__ roff, const float* __restrict__ ndst,
                      u16* __restrict__ outb, int N)
{
  const int wid = threadIdx.x >> 6;
  const int lane = threadIdx.x & 63;
  const int node = blockIdx.x * 4 + wid;
  if (node >= N) return;                 // wave-uniform
  const int h = lane >> 5;
  const int q = lane & 31;
  const uint2* fb2 = (const uint2*)fb;
  float4 acc = make_float4(0.f, 0.f, 0.f, 0.f);
  if (h == 0) {                          // self term (pre-scaled row)
    uint2 u = fb2[(size_t)node * 32 + q];
    acc.x = BF_LO(u.x); acc.y = BF_HI(u.x);
    acc.z = BF_LO(u.y); acc.w = BF_HI(u.y);
  }
  const int beg = roff[node], end = roff[node + 1];
  for (int e0 = beg; e0 < end; e0 += 64) {
    const int cnt = min(64, end - e0);   // wave-uniform
    int id = (lane < cnt) ? (int)eidx[e0 + lane] : 0;
    int j = 0;
    for (; j + 16 <= cnt; j += 16) {     // 8 row-reads in flight per half-wave
      int s0 = __shfl(id, j + 0 + h);
      int s1 = __shfl(id, j + 2 + h);
      int s2 = __shfl(id, j + 4 + h);
      int s3 = __shfl(id, j + 6 + h);
      int s4 = __shfl(id, j + 8 + h);
      int s5 = __shfl(id, j + 10 + h);
      int s6 = __shfl(id, j + 12 + h);
      int s7 = __shfl(id, j + 14 + h);
      uint2 u0 = fb2[(size_t)s0 * 32 + q];
      uint2 u1 = fb2[(size_t)s1 * 32 + q];
      uint2 u2 = fb2[(size_t)s2 * 32 + q];
      uint2 u3 = fb2[(size_t)s3 * 32 + q];
      uint2 u4 = fb2[(size_t)s4 * 32 + q];
      uint2 u5 = fb2[(size_t)s5 * 32 + q];
      uint2 u6 = fb2[(size_t)s6 * 32 + q];
      uint2 u7 = fb2[(size_t)s7 * 32 + q];
      acc.x += BF_LO(u0.x); acc.y += BF_HI(u0.x); acc.z += BF_LO(u0.y); acc.w += BF_HI(u0.y);
      acc.x += BF_LO(u1.x); acc.y += BF_HI(u1.x); acc.z += BF_LO(u1.y); acc.w += BF_HI(u1.y);
      acc.x += BF_LO(u2.x); acc.y += BF_HI(u2.x); acc.z += BF_LO(u2.y); acc.w += BF_HI(u2.y);
      acc.x += BF_LO(u3.x); acc.y += BF_HI(u3.x); acc.z += BF_LO(u3.y); acc.w += BF_HI(u3.y);
      acc.x += BF_LO(u4.x); acc.y += BF_HI(u4.x); acc.z += BF_LO(u4.y); acc.w += BF_HI(u4.y);
      acc.x += BF_LO(u5.x); acc.y += BF_HI(u5.x); acc.z += BF_LO(u5.y); acc.w += BF_HI(u5.y);
      acc.x += BF_LO(u6.x); acc.y += BF_HI(u6.x); acc.z += BF_LO(u6.y); acc.w += BF_HI(u6.y);
      acc.x += BF_LO(u7.x); acc.y += BF_HI(u7.x); acc.z += BF_LO(u7.y); acc.w += BF_HI(u7.y);
    }
    for (; j < cnt; j += 2) {            // tail: shfl UNCONDITIONAL, load guarded
      int ej = j + h;
      int s = __shfl(id, ej & 63);
      if (ej < cnt) {
        uint2 u = fb2[(size_t)s * 32 + q];
        acc.x += BF_LO(u.x); acc.y += BF_HI(u.x);
        acc.z += BF_LO(u.y); acc.w += BF_HI(u.y);
      }
    }
  }
  acc.x += __shfl_xor(acc.x, 32);
  acc.y += __shfl_xor(acc.y, 32);
  acc.z += __shfl_xor(acc.z, 32);
  acc.w += __shfl_xor(acc.w, 32);
  if (h == 0) {
    float nd = ndst[node];
    ushort4 w;
    w.x = f2bf(acc.x * nd); w.y = f2bf(acc.y * nd);
    w.z = f2bf(acc.z * nd); w.w = f2bf(acc.w * nd);
    *(ushort4*)(outb + (size_t)node * D + q * 4) = w;
  }
}

// ---------------- GEMM (proven inner loop): bf16 A, fp32 W/acc ----------------
// A stage: per thread one uint4 = 8 bf16 covering As[row][fc*4 .. fc*4+7].

template<bool RELU_SCALE, bool BF_OUT>
__global__ __launch_bounds__(256)
void gemm128(const u16* __restrict__ A, const float* __restrict__ W,
             const float* __restrict__ bias, const float* __restrict__ nsrc,
             void* __restrict__ Cv, int N)
{
  __shared__ float As[64][36];
  __shared__ float Bs[32][128];
  const int t = threadIdx.x;
  const int tx = t & 15;
  const int ty = t >> 4;
  const int r0 = blockIdx.x * 64;
  float acc[4][8];
  #pragma unroll
  for (int j = 0; j < 4; ++j)
    #pragma unroll
    for (int cc = 0; cc < 8; ++cc) acc[j][cc] = 0.f;

  for (int kc = 0; kc < D; kc += 32) {
    __syncthreads();
    {                                      // stage A: 64 rows x 32 bf16
      int q2 = t * 2;                      // uint2-granule index (0,2,..510)
      int row = q2 >> 3;
      int fc = q2 & 7;                     // even
      int gr = r0 + row; if (gr > N - 1) gr = N - 1;
      uint4 u = *(const uint4*)(A + (size_t)gr * D + kc + fc * 4);
      float4 f0 = make_float4(BF_LO(u.x), BF_HI(u.x), BF_LO(u.y), BF_HI(u.y));
      float4 f1 = make_float4(BF_LO(u.z), BF_HI(u.z), BF_LO(u.w), BF_HI(u.w));
      *(float4*)(&As[row][fc * 4]) = f0;
      *(float4*)(&As[row][fc * 4 + 4]) = f1;
    }
    #pragma unroll
    for (int m = 0; m < 4; ++m) {          // stage B: 32 x 128 fp32
      int q = t + 256 * m;
      int kk = q >> 5;
      int fc = q & 31;
      float4 v = *(const float4*)(W + (size_t)(kc + kk) * D + fc * 4);
      *(float4*)(&Bs[kk][fc * 4]) = v;
    }
    __syncthreads();
    #pragma unroll
    for (int k = 0; k < 32; ++k) {
      float a0 = As[ty * 4 + 0][k];
      float a1 = As[ty * 4 + 1][k];
      float a2 = As[ty * 4 + 2][k];
      float a3 = As[ty * 4 + 3][k];
      float4 bv0 = *(const float4*)(&Bs[k][tx * 4]);
      float4 bv1 = *(const float4*)(&Bs[k][64 + tx * 4]);
      float bb[8] = {bv0.x, bv0.y, bv0.z, bv0.w, bv1.x, bv1.y, bv1.z, bv1.w};
      #pragma unroll
      for (int cc = 0; cc < 8; ++cc) {
        acc[0][cc] += a0 * bb[cc];
        acc[1][cc] += a1 * bb[cc];
        acc[2][cc] += a2 * bb[cc];
        acc[3][cc] += a3 * bb[cc];
      }
    }
  }

  float4 bb0 = *(const float4*)(bias + tx * 4);
  float4 bb1 = *(const float4*)(bias + 64 + tx * 4);
  float bb[8] = {bb0.x, bb0.y, bb0.z, bb0.w, bb1.x, bb1.y, bb1.z, bb1.w};
  #pragma unroll
  for (int j = 0; j < 4; ++j) {
    int gr = r0 + ty * 4 + j;
    if (gr < N) {
      float s = RELU_SCALE ? nsrc[gr] : 1.0f;
      float o[8];
      #pragma unroll
      for (int cc = 0; cc < 8; ++cc) {
        float v = acc[j][cc] + bb[cc];
        if (RELU_SCALE) v = fmaxf(v, 0.f) * s;
        o[cc] = v;
      }
      if (BF_OUT) {
        u16* Cb = (u16*)Cv;
        ushort4 w0, w1;
        w0.x = f2bf(o[0]); w0.y = f2bf(o[1]); w0.z = f2bf(o[2]); w0.w = f2bf(o[3]);
        w1.x = f2bf(o[4]); w1.y = f2bf(o[5]); w1.z = f2bf(o[6]); w1.w = f2bf(o[7]);
        *(ushort4*)(Cb + (size_t)gr * D + tx * 4) = w0;
        *(ushort4*)(Cb + (size_t)gr * D + 64 + tx * 4) = w1;
      } else {
        float* C = (float*)Cv;
        *(float4*)(C + (size_t)gr * D + tx * 4) = make_float4(o[0], o[1], o[2], o[3]);
        *(float4*)(C + (size_t)gr * D + 64 + tx * 4) = make_float4(o[4], o[5], o[6], o[7]);
      }
    }
  }
}

// ---------------- launch ----------------
// ws layout (32.6MB <= proven 33.2MB), lifetime-disjoint aliases on one stream:
//   p0 [6.4MB]:  psrc u16 (hist1..reduce) -> esrc u16 3.2MB (scatter..gather2)
//   p1 [12.8MB]: pdst u16 6.4MB (hist2..scatter) -> h1bf 12.8MB (gemm1..gather2)
//   p2 [12.8MB]: featbf (convert..gather1) -> agg2 bf16 (gather2..gemm2)
//   d_out upper half [12.8MB]: agg1 bf16 (gather1..gemm1); gemm2 rewrites all of d_out.

extern "C" void kernel_launch(void* const* d_in, const int* in_sizes, int n_in,
                              void* d_out, int out_size, void* d_ws, size_t ws_size,
                              hipStream_t stream) {
  const float* feat = (const float*)d_in[0];
  const float* W1   = (const float*)d_in[1];
  const float* b1   = (const float*)d_in[2];
  const float* W2   = (const float*)d_in[3];
  const float* b2   = (const float*)d_in[4];
  const int*   src  = (const int*)d_in[5];
  const int*   dst  = (const int*)d_in[6];
  const int N = in_sizes[0] / D;
  const int E = in_sizes[5];
  float* out = (float*)d_out;

  const int binsR = (N + RANGES - 1) / RANGES;               // 12500
  const int chunkE = (((E + CHUNKS - 1) / CHUNKS) + 3) & ~3; // 25000

  auto align256 = [](size_t x) { return (x + 255) & ~(size_t)255; };
  char* p = (char*)d_ws;
  char* p0 = p;  p += align256((size_t)CHUNKS * N * 2);      // 6.4 MB
  char* p1 = p;  p += align256((size_t)N * D * 2);           // 12.8 MB
  char* p2 = p;  p += align256((size_t)N * D * 2);           // 12.8 MB
  int*   deg_in  = (int*)p;   p += align256((size_t)N * 4);
  int*   row_off = (int*)p;   p += align256((size_t)(N + 1) * 4);
  float* nsrc    = (float*)p; p += align256((size_t)N * 4);
  float* ndst    = (float*)p; p += align256((size_t)N * 4);
  int*   bsum    = (int*)p;   p += 256;

  u16*      psrc   = (u16*)p0;      // dies after reduce
  u16*      esrc   = (u16*)p0;      // written by scatter
  u16*      pdst   = (u16*)p1;      // dies after scatter
  u16*      h1bf   = (u16*)p1;      // written by gemm1
  unsigned* featbf = (unsigned*)p2; // dies after gather1
  u16*      agg2   = (u16*)p2;      // written by gather2
  u16*      agg1   = (u16*)((char*)d_out + (size_t)N * D * 2); // d_out upper half

  const int nblk = (N + 1023) / 1024;   // 49 (<= 64 for scan2)

  hist_kernel<<<RANGES * CHUNKS, 1024, 0, stream>>>(src, psrc, E, N, binsR, chunkE);
  hist_kernel<<<RANGES * CHUNKS, 1024, 0, stream>>>(dst, pdst, E, N, binsR, chunkE);
  reduce_kernel<<<(N + 255) / 256, 256, 0, stream>>>(psrc, pdst, deg_in, nsrc, ndst, N);
  convert_kernel<<<(N * D / 4 + 255) / 256, 256, 0, stream>>>(feat, nsrc, featbf, N * D / 4);
  scan1_kernel<<<nblk, 1024, 0, stream>>>(deg_in, row_off, bsum, N);
  scan2_kernel<<<1, 64, 0, stream>>>(bsum, row_off + N, nblk);
  scan3_kernel<<<nblk, 1024, 0, stream>>>(row_off, bsum, N);
  scatter_kernel<<<RANGES * CHUNKS, 1024, 0, stream>>>(src, dst, pdst, row_off, esrc, E, N, binsR, chunkE);

  // layer 1: agg(bf16) -> agg1 (d_out upper half), gemm(bf16 A) -> h1bf (bf16, relu*nsrc)
  gather_bf_kernel<<<(N + 3) / 4, 256, 0, stream>>>(featbf, esrc, row_off, ndst, agg1, N);
  gemm128<true, true><<<(N + 63) / 64, 256, 0, stream>>>(agg1, W1, b1, nsrc, h1bf, N);
  // layer 2: agg(bf16) -> agg2 (p2), gemm(bf16 A) -> d_out fp32
  gather_bf_kernel<<<(N + 3) / 4, 256, 0, stream>>>((const unsigned*)h1bf, esrc, row_off, ndst, agg2, N);
  gemm128<false, false><<<(N + 63) / 64, 256, 0, stream>>>(agg2, W2, b2, nsrc, out, N);
}

// Round 9
// 297.538 us; speedup vs baseline: 2.0212x; 1.0300x over previous
//
#include <hip/hip_runtime.h>

#define D 128
#define RANGES 4
#define CHUNKS 64
#define BINS_MAX 12512   // >= ceil(50000/4)

typedef unsigned short u16;
typedef __attribute__((ext_vector_type(8))) short short8;   // 8 bf16 (4 VGPRs)
typedef __attribute__((ext_vector_type(4))) float f32x4;

// ---------------- helpers ----------------

__device__ __forceinline__ u16 f2bf(float x) {   // RNE fp32->bf16
  unsigned u = __float_as_uint(x);
  u += 0x7fffu + ((u >> 16) & 1u);
  return (u16)(u >> 16);
}
#define BF_LO(u) __uint_as_float((u) << 16)
#define BF_HI(u) __uint_as_float((u) & 0xffff0000u)

// ---------------- CSR build, stage 1: per-chunk LDS histograms (proven) -------

__global__ __launch_bounds__(1024)
void hist_kernel(const int* __restrict__ keys, u16* __restrict__ part,
                 int E, int N, int binsR, int chunkE)
{
  __shared__ int hist[BINS_MAX];
  const int b = blockIdx.x;
  const int r = b & (RANGES - 1);
  const int k = b >> 2;
  const int lo = r * binsR;
  const int hi = min(N, lo + binsR);
  const int nb = hi - lo;
  for (int i = threadIdx.x; i < nb; i += 1024) hist[i] = 0;
  __syncthreads();
  const int e0 = k * chunkE;
  const int e1 = min(E, e0 + chunkE);
  for (int e = e0 + threadIdx.x; e < e1; e += 1024) {
    int v = keys[e];
    if (v >= lo && v < hi) atomicAdd(&hist[v - lo], 1);
  }
  __syncthreads();
  for (int i = threadIdx.x; i < nb; i += 1024)
    part[(size_t)k * N + lo + i] = (u16)hist[i];
}

// per bin: out-deg -> nsrc; in-deg -> ndst, deg_in; pdst -> exclusive prefix over chunks
__global__ void reduce_kernel(const u16* __restrict__ psrc, u16* __restrict__ pdst,
                              int* __restrict__ deg_in, float* __restrict__ nsrc,
                              float* __restrict__ ndst, int N)
{
  int bin = blockIdx.x * blockDim.x + threadIdx.x;
  if (bin >= N) return;
  int runs = 0, rund = 0;
  for (int k = 0; k < CHUNKS; ++k) {
    runs += psrc[(size_t)k * N + bin];
    int vd = pdst[(size_t)k * N + bin];
    pdst[(size_t)k * N + bin] = (u16)rund;
    rund += vd;
  }
  deg_in[bin] = rund;
  nsrc[bin] = rsqrtf((float)runs + 1.0f);   // +1 self-loop
  ndst[bin] = rsqrtf((float)rund + 1.0f);
}

// ---------------- hierarchical exclusive scan (proven): deg_in -> roff --------

__global__ __launch_bounds__(1024)
void scan1_kernel(const int* __restrict__ din, int* __restrict__ roff,
                  int* __restrict__ bsum, int N)
{
  __shared__ int wsum[16];
  const int t = threadIdx.x, lane = t & 63, wid = t >> 6;
  const int i = blockIdx.x * 1024 + t;
  int v = (i < N) ? din[i] : 0;
  int x = v;
  #pragma unroll
  for (int off = 1; off < 64; off <<= 1) {
    int u = __shfl_up(x, off);
    if (lane >= off) x += u;
  }
  if (lane == 63) wsum[wid] = x;
  __syncthreads();
  if (wid == 0) {
    int y = (lane < 16) ? wsum[lane] : 0;
    int z = y;
    #pragma unroll
    for (int off = 1; off < 16; off <<= 1) {
      int u = __shfl_up(z, off);
      if (lane >= off) z += u;
    }
    if (lane < 16) wsum[lane] = z - y;
    if (lane == 15) bsum[blockIdx.x] = z;
  }
  __syncthreads();
  if (i < N) roff[i] = wsum[wid] + (x - v);
}

__global__ void scan2_kernel(int* __restrict__ bsum, int* __restrict__ roffN, int nb)
{
  const int t = threadIdx.x;  // 64 threads
  int v = (t < nb) ? bsum[t] : 0;
  int x = v;
  #pragma unroll
  for (int off = 1; off < 64; off <<= 1) {
    int u = __shfl_up(x, off);
    if (t >= off) x += u;
  }
  if (t < nb) bsum[t] = x - v;
  if (t == 63) *roffN = x;
}

__global__ __launch_bounds__(1024)
void scan3_kernel(int* __restrict__ roff, const int* __restrict__ bsum, int N)
{
  const int i = blockIdx.x * 1024 + threadIdx.x;
  if (i < N) roff[i] += bsum[i >> 10];
}

// ---------------- scatter (proven): LDS cursor; u16 edge values --------------

__global__ __launch_bounds__(1024)
void scatter_kernel(const int* __restrict__ src, const int* __restrict__ dst,
                    const u16* __restrict__ pdst, const int* __restrict__ roff,
                    u16* __restrict__ eout, int E, int N, int binsR, int chunkE)
{
  __shared__ int cur[BINS_MAX];
  const int b = blockIdx.x;
  const int r = b & (RANGES - 1);
  const int k = b >> 2;
  const int lo = r * binsR;
  const int hi = min(N, lo + binsR);
  const int nb = hi - lo;
  for (int i = threadIdx.x; i < nb; i += 1024)
    cur[i] = roff[lo + i] + (int)pdst[(size_t)k * N + lo + i];
  __syncthreads();
  const int e0 = k * chunkE;
  const int e1 = min(E, e0 + chunkE);
  for (int e = e0 + threadIdx.x; e < e1; e += 1024) {
    int d = dst[e];
    if (d >= lo && d < hi) eout[atomicAdd(&cur[d - lo], 1)] = (u16)src[e];
  }
}

// ---------------- fp32 -> bf16 pack, pre-scaled by nsrc[row] (proven) --------

__global__ __launch_bounds__(256)
void convert_kernel(const float* __restrict__ f, const float* __restrict__ nsrc,
                    unsigned* __restrict__ fb, int n4)
{
  const int i = blockIdx.x * blockDim.x + threadIdx.x;
  if (i < n4) {
    float s = nsrc[i >> 5];
    float4 v = ((const float4*)f)[i];
    uint2 o;
    o.x = (unsigned)f2bf(v.x * s) | ((unsigned)f2bf(v.y * s) << 16);
    o.y = (unsigned)f2bf(v.z * s) | ((unsigned)f2bf(v.w * s) << 16);
    ((uint2*)fb)[i] = o;
  }
}

// ---------------- W (fp32 [K][Ncol]) -> Wt (bf16 [Ncol][K]) -------------------
// grid 256: blocks 0-127 -> W1 row k; 128-255 -> W2. 128 threads = col n.

__global__ __launch_bounds__(128)
void wtrans_kernel(const float* __restrict__ W1, const float* __restrict__ W2,
                   u16* __restrict__ Wt1, u16* __restrict__ Wt2)
{
  const int k = blockIdx.x & 127;
  const float* W = (blockIdx.x < 128) ? W1 : W2;
  u16* Wt = (blockIdx.x < 128) ? Wt1 : Wt2;
  const int n = threadIdx.x;
  Wt[n * 128 + k] = f2bf(W[k * 128 + n]);
}

// ---------------- aggregation (proven, round-8 verbatim) ---------------------

__global__ __launch_bounds__(256)
void gather_bf_kernel(const unsigned* __restrict__ fb, const u16* __restrict__ eidx,
                      const int* __restrict__ roff, const float* __restrict__ ndst,
                      u16* __restrict__ outb, int N)
{
  const int wid = threadIdx.x >> 6;
  const int lane = threadIdx.x & 63;
  const int node = blockIdx.x * 4 + wid;
  if (node >= N) return;                 // wave-uniform
  const int h = lane >> 5;
  const int q = lane & 31;
  const uint2* fb2 = (const uint2*)fb;
  float4 acc = make_float4(0.f, 0.f, 0.f, 0.f);
  if (h == 0) {                          // self term (pre-scaled row)
    uint2 u = fb2[(size_t)node * 32 + q];
    acc.x = BF_LO(u.x); acc.y = BF_HI(u.x);
    acc.z = BF_LO(u.y); acc.w = BF_HI(u.y);
  }
  const int beg = roff[node], end = roff[node + 1];
  for (int e0 = beg; e0 < end; e0 += 64) {
    const int cnt = min(64, end - e0);   // wave-uniform
    int id = (lane < cnt) ? (int)eidx[e0 + lane] : 0;
    int j = 0;
    for (; j + 16 <= cnt; j += 16) {     // 8 row-reads in flight per half-wave
      int s0 = __shfl(id, j + 0 + h);
      int s1 = __shfl(id, j + 2 + h);
      int s2 = __shfl(id, j + 4 + h);
      int s3 = __shfl(id, j + 6 + h);
      int s4 = __shfl(id, j + 8 + h);
      int s5 = __shfl(id, j + 10 + h);
      int s6 = __shfl(id, j + 12 + h);
      int s7 = __shfl(id, j + 14 + h);
      uint2 u0 = fb2[(size_t)s0 * 32 + q];
      uint2 u1 = fb2[(size_t)s1 * 32 + q];
      uint2 u2 = fb2[(size_t)s2 * 32 + q];
      uint2 u3 = fb2[(size_t)s3 * 32 + q];
      uint2 u4 = fb2[(size_t)s4 * 32 + q];
      uint2 u5 = fb2[(size_t)s5 * 32 + q];
      uint2 u6 = fb2[(size_t)s6 * 32 + q];
      uint2 u7 = fb2[(size_t)s7 * 32 + q];
      acc.x += BF_LO(u0.x); acc.y += BF_HI(u0.x); acc.z += BF_LO(u0.y); acc.w += BF_HI(u0.y);
      acc.x += BF_LO(u1.x); acc.y += BF_HI(u1.x); acc.z += BF_LO(u1.y); acc.w += BF_HI(u1.y);
      acc.x += BF_LO(u2.x); acc.y += BF_HI(u2.x); acc.z += BF_LO(u2.y); acc.w += BF_HI(u2.y);
      acc.x += BF_LO(u3.x); acc.y += BF_HI(u3.x); acc.z += BF_LO(u3.y); acc.w += BF_HI(u3.y);
      acc.x += BF_LO(u4.x); acc.y += BF_HI(u4.x); acc.z += BF_LO(u4.y); acc.w += BF_HI(u4.y);
      acc.x += BF_LO(u5.x); acc.y += BF_HI(u5.x); acc.z += BF_LO(u5.y); acc.w += BF_HI(u5.y);
      acc.x += BF_LO(u6.x); acc.y += BF_HI(u6.x); acc.z += BF_LO(u6.y); acc.w += BF_HI(u6.y);
      acc.x += BF_LO(u7.x); acc.y += BF_HI(u7.x); acc.z += BF_LO(u7.y); acc.w += BF_HI(u7.y);
    }
    for (; j < cnt; j += 2) {            // tail: shfl UNCONDITIONAL, load guarded
      int ej = j + h;
      int s = __shfl(id, ej & 63);
      if (ej < cnt) {
        uint2 u = fb2[(size_t)s * 32 + q];
        acc.x += BF_LO(u.x); acc.y += BF_HI(u.x);
        acc.z += BF_LO(u.y); acc.w += BF_HI(u.y);
      }
    }
  }
  acc.x += __shfl_xor(acc.x, 32);
  acc.y += __shfl_xor(acc.y, 32);
  acc.z += __shfl_xor(acc.z, 32);
  acc.w += __shfl_xor(acc.w, 32);
  if (h == 0) {
    float nd = ndst[node];
    ushort4 w;
    w.x = f2bf(acc.x * nd); w.y = f2bf(acc.y * nd);
    w.z = f2bf(acc.z * nd); w.w = f2bf(acc.w * nd);
    *(ushort4*)(outb + (size_t)node * D + q * 4) = w;
  }
}

// ---------------- MFMA GEMM: C[N,128] = A_bf16[N,128] @ Wt_bf16^T + b ---------
// One wave = one 16-row tile, 8 col-tiles x 4 K-steps of mfma_f32_16x16x32_bf16.
// A-frag: lane l loads A[row = tile*16 + (l&15)][k = kc + (l>>4)*8 .. +7] (uint4).
// B-frag: lane l loads Wt[col = c*16 + (l&15)][k = kc + (l>>4)*8 .. +7] (uint4).
// C/D layout (HW-verified): col = lane&15, row-in-tile = (lane>>4)*4 + reg.
// No LDS, no barriers.

template<bool RELU_SCALE, bool BF_OUT>
__global__ __launch_bounds__(256)
void gemm_mfma(const u16* __restrict__ A, const u16* __restrict__ Wt,
               const float* __restrict__ bias, const float* __restrict__ nsrc,
               void* __restrict__ Cv, int N)
{
  const int lane = threadIdx.x & 63;
  const int wv   = threadIdx.x >> 6;
  const int tile = blockIdx.x * 4 + wv;
  if (tile * 16 >= N) return;            // wave-uniform
  const int m  = lane & 15;
  const int kb = lane >> 4;              // 0..3
  int arow = tile * 16 + m; if (arow > N - 1) arow = N - 1;   // clamped A row
  f32x4 acc[8];
  #pragma unroll
  for (int c = 0; c < 8; ++c) acc[c] = (f32x4){0.f, 0.f, 0.f, 0.f};
  #pragma unroll
  for (int kc = 0; kc < D; kc += 32) {
    short8 a = *(const short8*)(A + (size_t)arow * D + kc + kb * 8);
    #pragma unroll
    for (int c = 0; c < 8; ++c) {
      short8 b = *(const short8*)(Wt + (size_t)(c * 16 + m) * D + kc + kb * 8);
      acc[c] = __builtin_amdgcn_mfma_f32_16x16x32_bf16(a, b, acc[c], 0, 0, 0);
    }
  }
  // epilogue: rows tile*16 + kb*4 + j (j=0..3), col = c*16 + m
  float ns[4];
  #pragma unroll
  for (int j = 0; j < 4; ++j) {
    int orow = tile * 16 + kb * 4 + j;
    ns[j] = (RELU_SCALE && orow < N) ? nsrc[orow] : 1.0f;
  }
  #pragma unroll
  for (int c = 0; c < 8; ++c) {
    const int col = c * 16 + m;
    const float bb = bias[col];
    #pragma unroll
    for (int j = 0; j < 4; ++j) {
      int orow = tile * 16 + kb * 4 + j;
      if (orow < N) {
        float v = acc[c][j] + bb;
        if (RELU_SCALE) v = fmaxf(v, 0.f) * ns[j];
        if (BF_OUT) ((u16*)Cv)[(size_t)orow * D + col] = f2bf(v);
        else        ((float*)Cv)[(size_t)orow * D + col] = v;
      }
    }
  }
}

// ---------------- launch ----------------
// ws layout (32.7MB <= proven 33.2MB), lifetime-disjoint aliases on one stream:
//   p0 [6.4MB]:  psrc u16 (hist1..reduce) -> esrc u16 3.2MB (scatter..gather2)
//   p1 [12.8MB]: pdst u16 6.4MB (hist2..scatter) -> h1bf 12.8MB (gemm1..gather2)
//   p2 [12.8MB]: featbf (convert..gather1) -> agg2 bf16 (gather2..gemm2)
//   d_out upper half [12.8MB]: agg1 bf16 (gather1..gemm1); gemm2 rewrites all of d_out.
//   smalls: deg_in, row_off, nsrc, ndst, bsum, wt1, wt2 (bf16 W^T, 32KB each)

extern "C" void kernel_launch(void* const* d_in, const int* in_sizes, int n_in,
                              void* d_out, int out_size, void* d_ws, size_t ws_size,
                              hipStream_t stream) {
  const float* feat = (const float*)d_in[0];
  const float* W1   = (const float*)d_in[1];
  const float* b1   = (const float*)d_in[2];
  const float* W2   = (const float*)d_in[3];
  const float* b2   = (const float*)d_in[4];
  const int*   src  = (const int*)d_in[5];
  const int*   dst  = (const int*)d_in[6];
  const int N = in_sizes[0] / D;
  const int E = in_sizes[5];
  float* out = (float*)d_out;

  const int binsR = (N + RANGES - 1) / RANGES;               // 12500
  const int chunkE = (((E + CHUNKS - 1) / CHUNKS) + 3) & ~3; // 25000

  auto align256 = [](size_t x) { return (x + 255) & ~(size_t)255; };
  char* p = (char*)d_ws;
  char* p0 = p;  p += align256((size_t)CHUNKS * N * 2);      // 6.4 MB
  char* p1 = p;  p += align256((size_t)N * D * 2);           // 12.8 MB
  char* p2 = p;  p += align256((size_t)N * D * 2);           // 12.8 MB
  int*   deg_in  = (int*)p;   p += align256((size_t)N * 4);
  int*   row_off = (int*)p;   p += align256((size_t)(N + 1) * 4);
  float* nsrc    = (float*)p; p += align256((size_t)N * 4);
  float* ndst    = (float*)p; p += align256((size_t)N * 4);
  int*   bsum    = (int*)p;   p += 256;
  u16*   wt1     = (u16*)p;   p += align256((size_t)D * D * 2);
  u16*   wt2     = (u16*)p;   p += align256((size_t)D * D * 2);

  u16*      psrc   = (u16*)p0;      // dies after reduce
  u16*      esrc   = (u16*)p0;      // written by scatter
  u16*      pdst   = (u16*)p1;      // dies after scatter
  u16*      h1bf   = (u16*)p1;      // written by gemm1
  unsigned* featbf = (unsigned*)p2; // dies after gather1
  u16*      agg2   = (u16*)p2;      // written by gather2
  u16*      agg1   = (u16*)((char*)d_out + (size_t)N * D * 2); // d_out upper half

  const int nblk = (N + 1023) / 1024;   // 49 (<= 64 for scan2)
  const int gemm_grid = ((N + 15) / 16 + 3) / 4;

  wtrans_kernel<<<256, 128, 0, stream>>>(W1, W2, wt1, wt2);
  hist_kernel<<<RANGES * CHUNKS, 1024, 0, stream>>>(src, psrc, E, N, binsR, chunkE);
  hist_kernel<<<RANGES * CHUNKS, 1024, 0, stream>>>(dst, pdst, E, N, binsR, chunkE);
  reduce_kernel<<<(N + 255) / 256, 256, 0, stream>>>(psrc, pdst, deg_in, nsrc, ndst, N);
  convert_kernel<<<(N * D / 4 + 255) / 256, 256, 0, stream>>>(feat, nsrc, featbf, N * D / 4);
  scan1_kernel<<<nblk, 1024, 0, stream>>>(deg_in, row_off, bsum, N);
  scan2_kernel<<<1, 64, 0, stream>>>(bsum, row_off + N, nblk);
  scan3_kernel<<<nblk, 1024, 0, stream>>>(row_off, bsum, N);
  scatter_kernel<<<RANGES * CHUNKS, 1024, 0, stream>>>(src, dst, pdst, row_off, esrc, E, N, binsR, chunkE);

  // layer 1: agg(bf16) -> agg1 (d_out upper half), mfma-gemm -> h1bf (bf16, relu*nsrc)
  gather_bf_kernel<<<(N + 3) / 4, 256, 0, stream>>>(featbf, esrc, row_off, ndst, agg1, N);
  gemm_mfma<true, true><<<gemm_grid, 256, 0, stream>>>(agg1, wt1, b1, nsrc, h1bf, N);
  // layer 2: agg(bf16) -> agg2 (p2), mfma-gemm -> d_out fp32
  gather_bf_kernel<<<(N + 3) / 4, 256, 0, stream>>>((const unsigned*)h1bf, esrc, row_off, ndst, agg2, N);
  gemm_mfma<false, false><<<gemm_grid, 256, 0, stream>>>(agg2, wt2, b2, nsrc, out, N);
}